// Round 2
// baseline (264.178 us; speedup 1.0000x reference)
//
#include <hip/hip_runtime.h>
#include <math.h>

typedef __bf16 bf16x8 __attribute__((ext_vector_type(8)));
typedef float f32x4 __attribute__((ext_vector_type(4)));
typedef unsigned short u16x8 __attribute__((ext_vector_type(8)));
typedef unsigned short u16x4v __attribute__((ext_vector_type(4)));

constexpr int NIMG = 16384;   // H*W
constexpr int HPITCH = 130;   // padded row pitch (tokens) for g_h
constexpr int HROW = HPITCH*256; // shorts per padded image row

__device__ __forceinline__ unsigned short f2bf(float f){
  unsigned u = __builtin_bit_cast(unsigned, f);
  u += 0x7fffu + ((u>>16)&1u);
  return (unsigned short)(u>>16);
}
__device__ __forceinline__ unsigned pack2(float a, float b){
  return (unsigned)f2bf(a) | ((unsigned)f2bf(b)<<16);
}
__device__ __forceinline__ float bf2f(unsigned short h){
  unsigned u = ((unsigned)h)<<16;
  return __builtin_bit_cast(float, u);
}
__device__ __forceinline__ bf16x8 ldfrag_g(const unsigned short* p){
  u16x8 v = *reinterpret_cast<const u16x8*>(p);
  return __builtin_bit_cast(bf16x8, v);
}
__device__ __forceinline__ f32x4 mfma16(bf16x8 a, bf16x8 b, f32x4 c){
  return __builtin_amdgcn_mfma_f32_16x16x32_bf16(a, b, c, 0, 0, 0);
}
__device__ __forceinline__ f32x4 bfcvt4(uint2 q){
  f32x4 r;
  r[0] = __builtin_bit_cast(float, q.x << 16);
  r[1] = __builtin_bit_cast(float, q.x & 0xffff0000u);
  r[2] = __builtin_bit_cast(float, q.y << 16);
  r[3] = __builtin_bit_cast(float, q.y & 0xffff0000u);
  return r;
}

// ============ k0: weights fp32 -> bf16 MFMA fragment layout (+ tap repack) ============
__global__ __launch_bounds__(64) void k0_wfrag(
  const float* __restrict__ Wk, const float* __restrict__ Wq,
  const float* __restrict__ Wv, const float* __restrict__ Wr,
  const float* __restrict__ W1, const float* __restrict__ W2,
  const float* __restrict__ dww, float* __restrict__ dwp,
  unsigned short* __restrict__ wf)
{
  const int bid = blockIdx.x, l = threadIdx.x;
  if (bid == 96){
    // repack taps: dwp[group g=0..63][tap j=0..8][ch c=0..3] ; channel f = g*4+c
    #pragma unroll
    for (int c=0;c<4;++c){
      int f = l*4 + c;
      #pragma unroll
      for (int j=0;j<9;++j) dwp[l*36 + j*4 + c] = dww[f*9+j];
    }
    return;
  }
  const float* src; int K, nt, ks; unsigned short* dst;
  if (bid < 32){
    int w = bid>>3, f = bid&7;
    src = (w==0)?Wk:(w==1)?Wq:(w==2)?Wv:Wr;
    K = 64; nt = f>>1; ks = f&1;
    dst = wf + w*4096 + f*512;
  } else if (bid < 64){
    int f = bid-32; src = W1; K = 64; nt = f>>1; ks = f&1;
    dst = wf + 16384 + f*512;
  } else {
    int f = bid-64; src = W2; K = 256; nt = f>>3; ks = f&7;
    dst = wf + 32768 + f*512;
  }
  u16x8 v;
  #pragma unroll
  for (int j=0;j<8;++j){
    int k = ks*32 + (l>>4)*8 + j;
    int n = nt*16 + (l&15);
    v[j] = f2bf(src[n*K + k]);
  }
  *reinterpret_cast<u16x8*>(dst + l*8) = v;
}

// ============ zhalo: zero g_h halo columns + shared zero-row ============
__global__ __launch_bounds__(256) void zhalo(unsigned* __restrict__ gh, unsigned* __restrict__ zr){
  int idx = blockIdx.x*256 + threadIdx.x;
  if (idx < 524288){
    int ch2 = idx & 127;
    int pos = idx >> 7;
    int side = pos & 1, row = pos >> 1;
    gh[(size_t)(row*HPITCH + side*(HPITCH-1))*128 + ch2] = 0;
  } else {
    int j = idx - 524288;
    if (j < HROW/2) zr[j] = 0;
  }
}

// ============ k1: LN1 + K/V proj (MFMA) + ctx accumulation (MFMA, LDS-transpose) ============
__global__ __launch_bounds__(256,2) void k1_ctx(
  const float* __restrict__ x, const float* __restrict__ g1, const float* __restrict__ be1,
  const float* __restrict__ bk, const float* __restrict__ bv,
  const unsigned short* __restrict__ wf,
  float* __restrict__ g_part, float* __restrict__ g_sump)
{
  __shared__ unsigned short tiles[4][4096];
  __shared__ float ctx_l[64*68];
  __shared__ float ssum_l[4][64];
  const int t = threadIdx.x, wid = t>>6, l = t&63;
  const int lg = l>>4, l15 = l&15;
  unsigned short* tile = tiles[wid];
  const int tok0 = blockIdx.x*512 + wid*128;

  bf16x8 WkF[8], WvF[8];
  #pragma unroll
  for (int f=0; f<8; ++f){
    WkF[f] = ldfrag_g(wf +    0 + f*512 + l*8);
    WvF[f] = ldfrag_g(wf + 8192 + f*512 + l*8);
  }
  float4 g1v  = *reinterpret_cast<const float4*>(&g1[l15*4]);
  float4 be1v = *reinterpret_cast<const float4*>(&be1[l15*4]);
  float bkv[4], bvv[4];
  #pragma unroll
  for (int ct=0; ct<4; ++ct){ bkv[ct]=bk[ct*16+l15]; bvv[ct]=bv[ct*16+l15]; }

  f32x4 acc[4][4];
  #pragma unroll
  for (int a=0;a<4;++a)
    #pragma unroll
    for (int b=0;b<4;++b) acc[a][b] = (f32x4){0.f,0.f,0.f,0.f};
  float sume[4] = {0.f,0.f,0.f,0.f};

  for (int tb=0; tb<2; ++tb){
    const int tbase = tok0 + tb*64;
    #pragma unroll
    for (int it=0; it<16; ++it){
      int row = it*4 + lg;
      float4 xv = *reinterpret_cast<const float4*>(&x[(size_t)(tbase+row)*64 + l15*4]);
      float s1 = xv.x+xv.y+xv.z+xv.w;
      float s2 = xv.x*xv.x + xv.y*xv.y + xv.z*xv.z + xv.w*xv.w;
      #pragma unroll
      for (int off=1; off<16; off<<=1){ s1 += __shfl_xor(s1,off,64); s2 += __shfl_xor(s2,off,64); }
      float mu = s1*(1.f/64.f);
      float rs = rsqrtf(s2*(1.f/64.f) - mu*mu + 1e-5f);
      uint2 pk = { pack2((xv.x-mu)*rs*g1v.x + be1v.x, (xv.y-mu)*rs*g1v.y + be1v.y),
                   pack2((xv.z-mu)*rs*g1v.z + be1v.z, (xv.w-mu)*rs*g1v.w + be1v.w) };
      *reinterpret_cast<uint2*>(&tile[row*64 + ((l15*4) ^ ((row&7)<<3))]) = pk;
    }
    bf16x8 aF[4][2];
    #pragma unroll
    for (int mt=0;mt<4;++mt){
      int row = mt*16+l15, sw=(row&7)<<3, ab=row*64;
      aF[mt][0] = __builtin_bit_cast(bf16x8, *reinterpret_cast<const u16x8*>(tile+ab+((     lg*8)^sw)));
      aF[mt][1] = __builtin_bit_cast(bf16x8, *reinterpret_cast<const u16x8*>(tile+ab+((32 + lg*8)^sw)));
    }
    #pragma unroll
    for (int half=0; half<2; ++half){
      #pragma unroll
      for (int m2=0;m2<2;++m2){
        const int mt = half*2+m2;
        #pragma unroll
        for (int ct=0;ct<4;++ct){
          f32x4 z = {0.f,0.f,0.f,0.f};
          z = mfma16(aF[mt][0], WkF[ct*2+0], z);
          z = mfma16(aF[mt][1], WkF[ct*2+1], z);
          float e0=__expf(z[0]+bkv[ct]), e1=__expf(z[1]+bkv[ct]);
          float e2=__expf(z[2]+bkv[ct]), e3=__expf(z[3]+bkv[ct]);
          sume[ct] += (e0+e1)+(e2+e3);
          const int c = ct*16+l15, sw = (c&7)<<3;
          const int cb = m2*16+lg*4;
          uint2 pe = { pack2(e0,e1), pack2(e2,e3) };
          *reinterpret_cast<uint2*>(&tile[c*64 + (cb ^ sw)]) = pe;
          f32x4 w = {0.f,0.f,0.f,0.f};
          w = mfma16(aF[mt][0], WvF[ct*2+0], w);
          w = mfma16(aF[mt][1], WvF[ct*2+1], w);
          uint2 pv = { pack2(w[0]+bvv[ct], w[1]+bvv[ct]), pack2(w[2]+bvv[ct], w[3]+bvv[ct]) };
          *reinterpret_cast<uint2*>(&tile[c*64 + ((32+cb) ^ sw)]) = pv;
        }
      }
      bf16x8 eA[4], vB[4];
      #pragma unroll
      for (int cm=0;cm<4;++cm){
        int row = cm*16+l15, sw=(row&7)<<3;
        eA[cm] = __builtin_bit_cast(bf16x8, *reinterpret_cast<const u16x8*>(tile + row*64 + ((     lg*8)^sw)));
        vB[cm] = __builtin_bit_cast(bf16x8, *reinterpret_cast<const u16x8*>(tile + row*64 + ((32 + lg*8)^sw)));
      }
      #pragma unroll
      for (int cm=0; cm<4; ++cm)
        #pragma unroll
        for (int jn=0; jn<4; ++jn)
          acc[cm][jn] = mfma16(eA[cm], vB[jn], acc[cm][jn]);
    }
  }
  #pragma unroll
  for (int ct=0; ct<4; ++ct){
    float s = sume[ct];
    s += __shfl_xor(s,16,64); s += __shfl_xor(s,32,64);
    if (lg==0) ssum_l[wid][ct*16+l15] = s;
  }
  #define CTX_RED(OP) \
    _Pragma("unroll") for (int cm=0;cm<4;++cm) \
    _Pragma("unroll") for (int jn=0;jn<4;++jn) \
    _Pragma("unroll") for (int r=0;r<4;++r) \
      ctx_l[(cm*16+lg*4+r)*68 + jn*16+l15] OP acc[cm][jn][r];
  if (wid==0){ CTX_RED(=) }  __syncthreads();
  if (wid==1){ CTX_RED(+=) } __syncthreads();
  if (wid==2){ CTX_RED(+=) } __syncthreads();
  if (wid==3){ CTX_RED(+=) } __syncthreads();
  #undef CTX_RED
  for (int i=t; i<4096; i+=256)
    g_part[(size_t)blockIdx.x*4096 + i] = ctx_l[(i>>6)*68 + (i&63)];
  if (t<64)
    g_sump[blockIdx.x*64 + t] = ssum_l[0][t]+ssum_l[1][t]+ssum_l[2][t]+ssum_l[3][t];
}

// ============ k15: reduce partials; ctxWr = (ctx_norm @ Wr^T) -> bf16 frags ============
__global__ __launch_bounds__(512) void k15_ctxwr(
  const float* __restrict__ g_part, const float* __restrict__ g_sump,
  const float* __restrict__ Wr, unsigned short* __restrict__ ctxWrF)
{
  __shared__ float sctx[4096];
  __shared__ float sWr[4096];
  __shared__ float sinv[64];
  const int b = blockIdx.x, t = threadIdx.x;
  if (t<64){
    float s=0.f;
    #pragma unroll 8
    for (int p=0;p<32;++p) s += g_sump[(b*32+p)*64 + t];
    sinv[t] = 1.f/s;
  }
  for (int idx=t; idx<4096; idx+=512){
    float s=0.f;
    #pragma unroll 8
    for (int p=0;p<32;++p) s += g_part[(size_t)(b*32+p)*4096 + idx];
    sctx[idx] = s;
  }
  __syncthreads();
  {
    int c = t>>3, d0 = (t&7)*8;
    float invc = sinv[c];
    #pragma unroll
    for (int dd=0; dd<8; ++dd){
      int d = d0+dd; float s = 0.f;
      #pragma unroll
      for (int v=0; v<64; ++v) s += sctx[c*64+v]*Wr[d*64+v];
      sWr[c*64+d] = s*invc;
    }
  }
  __syncthreads();
  {
    int f = t>>6, l = t&63, nt = f>>1, ks = f&1;
    u16x8 v;
    #pragma unroll
    for (int j=0;j<8;++j){
      int k = ks*32 + (l>>4)*8 + j;
      int n = nt*16 + (l&15);
      v[j] = f2bf(sWr[k*64+n]);
    }
    *reinterpret_cast<u16x8*>(ctxWrF + b*4096 + f*512 + l*8) = v;
  }
}

// ============ k2: LN1 + q-softmax + attn + residual + LN2 + W1 (nt2-outer phase B) ============
__global__ __launch_bounds__(256,2) void k2_attn_ffn1(
  const float* __restrict__ x,
  const float* __restrict__ g1, const float* __restrict__ be1,
  const float* __restrict__ bq, const float* __restrict__ br,
  const float* __restrict__ g2, const float* __restrict__ be2,
  const float* __restrict__ b1,
  const unsigned short* __restrict__ wf,
  const unsigned short* __restrict__ ctxWrF,
  unsigned short* __restrict__ g_txb, unsigned short* __restrict__ g_h)
{
  __shared__ unsigned short tiles[4][4096];
  const int t = threadIdx.x, wid = t>>6, l = t&63;
  const int l15 = l&15, lg = l>>4;
  unsigned short* tile = tiles[wid];
  const int tok0 = (blockIdx.x*4 + wid)*64;
  const int img  = blockIdx.x>>6;
  const int yrow = (tok0>>7)&127;
  const int xb   = tok0&127;
  const size_t hbase = ((size_t)(img*128 + yrow)*HPITCH + 1 + xb)*256;

  bf16x8 WqF[8], CWF[8];
  #pragma unroll
  for (int f=0; f<8; ++f){
    WqF[f] = ldfrag_g(wf + 4096 + f*512 + l*8);
    CWF[f] = ldfrag_g(ctxWrF + img*4096 + f*512 + l*8);
  }
  float4 g1v  = *reinterpret_cast<const float4*>(&g1[l15*4]);
  float4 be1v = *reinterpret_cast<const float4*>(&be1[l15*4]);
  float bqv[4], brv[4], g2v[4], be2v[4];
  #pragma unroll
  for (int nt=0; nt<4; ++nt){
    bqv[nt]=bq[nt*16+l15]; brv[nt]=br[nt*16+l15];
    g2v[nt]=g2[nt*16+l15]; be2v[nt]=be2[nt*16+l15];
  }
  float b1v[16];
  #pragma unroll
  for (int i=0;i<16;++i) b1v[i]=b1[i*16+l15];

  // ---- LN1 -> swizzled bf16 tile ----
  #pragma unroll
  for (int it=0; it<16; ++it){
    int row = it*4 + lg;
    float4 xv = *reinterpret_cast<const float4*>(&x[(size_t)(tok0+row)*64 + l15*4]);
    float s1 = xv.x+xv.y+xv.z+xv.w;
    float s2 = xv.x*xv.x + xv.y*xv.y + xv.z*xv.z + xv.w*xv.w;
    #pragma unroll
    for (int off=1; off<16; off<<=1){ s1 += __shfl_xor(s1,off,64); s2 += __shfl_xor(s2,off,64); }
    float mu = s1*(1.f/64.f);
    float rs = rsqrtf(s2*(1.f/64.f) - mu*mu + 1e-5f);
    uint2 pk = { pack2((xv.x-mu)*rs*g1v.x + be1v.x, (xv.y-mu)*rs*g1v.y + be1v.y),
                 pack2((xv.z-mu)*rs*g1v.z + be1v.z, (xv.w-mu)*rs*g1v.w + be1v.w) };
    *reinterpret_cast<uint2*>(&tile[row*64 + ((l15*4) ^ ((row&7)<<3))]) = pk;
  }

  // ---- phase A: per m-tile attn chain; leaves n2 in the tile ----
  for (int mt=0; mt<4; ++mt){
    const int arow = mt*16 + l15;
    const int asw  = (arow&7)<<3;
    const int abase= arow*64;
    bf16x8 a0 = __builtin_bit_cast(bf16x8, *reinterpret_cast<const u16x8*>(tile + abase + ((     lg*8) ^ asw)));
    bf16x8 a1 = __builtin_bit_cast(bf16x8, *reinterpret_cast<const u16x8*>(tile + abase + ((32 + lg*8) ^ asw)));
    f32x4 qa[4];
    #pragma unroll
    for (int nt=0; nt<4; ++nt){
      f32x4 z = {0.f,0.f,0.f,0.f};
      z = mfma16(a0, WqF[nt*2+0], z);
      z = mfma16(a1, WqF[nt*2+1], z);
      qa[nt] = z;
    }
    #pragma unroll
    for (int nt=0; nt<4; ++nt)
      #pragma unroll
      for (int r=0; r<4; ++r) qa[nt][r] += bqv[nt];
    float mx[4];
    #pragma unroll
    for (int r=0;r<4;++r) mx[r] = fmaxf(fmaxf(qa[0][r],qa[1][r]), fmaxf(qa[2][r],qa[3][r]));
    #pragma unroll
    for (int off=1; off<16; off<<=1)
      #pragma unroll
      for (int r=0;r<4;++r) mx[r] = fmaxf(mx[r], __shfl_xor(mx[r], off, 64));
    float sm[4] = {0.f,0.f,0.f,0.f};
    #pragma unroll
    for (int nt=0;nt<4;++nt)
      #pragma unroll
      for (int r=0;r<4;++r){ float e = __expf(qa[nt][r]-mx[r]); qa[nt][r]=e; sm[r]+=e; }
    #pragma unroll
    for (int off=1; off<16; off<<=1)
      #pragma unroll
      for (int r=0;r<4;++r) sm[r] += __shfl_xor(sm[r], off, 64);
    float inv[4];
    #pragma unroll
    for (int r=0;r<4;++r) inv[r] = 1.f/sm[r];
    #pragma unroll
    for (int nt=0;nt<4;++nt)
      #pragma unroll
      for (int r=0;r<4;++r){
        int row = mt*16 + lg*4 + r, col = nt*16 + l15;
        tile[row*64 + (col ^ ((row&7)<<3))] = f2bf(qa[nt][r]*inv[r]);
      }
    bf16x8 p0 = __builtin_bit_cast(bf16x8, *reinterpret_cast<const u16x8*>(tile + abase + ((     lg*8) ^ asw)));
    bf16x8 p1 = __builtin_bit_cast(bf16x8, *reinterpret_cast<const u16x8*>(tile + abase + ((32 + lg*8) ^ asw)));
    f32x4 ao[4];
    #pragma unroll
    for (int nt=0; nt<4; ++nt){
      f32x4 z = {0.f,0.f,0.f,0.f};
      z = mfma16(p0, CWF[nt*2+0], z);
      z = mfma16(p1, CWF[nt*2+1], z);
      ao[nt] = z;
    }
    float txv[4][4];
    float s1v[4] = {0.f,0.f,0.f,0.f}, s2v[4] = {0.f,0.f,0.f,0.f};
    #pragma unroll
    for (int nt=0;nt<4;++nt)
      #pragma unroll
      for (int r=0;r<4;++r){
        size_t row = (size_t)(tok0 + mt*16 + lg*4 + r);
        float v = ao[nt][r] + brv[nt] + x[row*64 + nt*16+l15];
        g_txb[row*64 + nt*16+l15] = f2bf(v);
        txv[nt][r] = v; s1v[r] += v; s2v[r] += v*v;
      }
    #pragma unroll
    for (int off=1; off<16; off<<=1)
      #pragma unroll
      for (int r=0;r<4;++r){ s1v[r] += __shfl_xor(s1v[r], off, 64); s2v[r] += __shfl_xor(s2v[r], off, 64); }
    #pragma unroll
    for (int r=0;r<4;++r){
      float mu2 = s1v[r]*(1.f/64.f);
      float rs  = rsqrtf(s2v[r]*(1.f/64.f) - mu2*mu2 + 1e-5f);
      s1v[r] = mu2; s2v[r] = rs;
    }
    #pragma unroll
    for (int nt=0;nt<4;++nt)
      #pragma unroll
      for (int r=0;r<4;++r){
        int row = mt*16 + lg*4 + r, col = nt*16 + l15;
        float n2 = (txv[nt][r]-s1v[r])*s2v[r]*g2v[nt] + be2v[nt];
        tile[row*64 + (col ^ ((row&7)<<3))] = f2bf(n2);
      }
  }

  // ---- phase B: h = n2 @ W1^T + b1 (nt2 outer: each W1 frag loaded ONCE) ----
  #pragma unroll 2
  for (int nt2=0; nt2<16; ++nt2){
    bf16x8 w0 = ldfrag_g(wf + 16384 + (nt2*2+0)*512 + l*8);
    bf16x8 w1 = ldfrag_g(wf + 16384 + (nt2*2+1)*512 + l*8);
    float bb = b1v[nt2];
    #pragma unroll
    for (int mt=0; mt<4; ++mt){
      const int arow = mt*16 + l15;
      const int asw  = (arow&7)<<3;
      const int abase= arow*64;
      bf16x8 n20 = __builtin_bit_cast(bf16x8, *reinterpret_cast<const u16x8*>(tile + abase + ((     lg*8) ^ asw)));
      bf16x8 n21 = __builtin_bit_cast(bf16x8, *reinterpret_cast<const u16x8*>(tile + abase + ((32 + lg*8) ^ asw)));
      f32x4 h = {bb,bb,bb,bb};
      h = mfma16(n20, w0, h);
      h = mfma16(n21, w1, h);
      #pragma unroll
      for (int r=0;r<4;++r)
        g_h[hbase + (size_t)(mt*16+lg*4+r)*256 + nt2*16 + l15] = f2bf(h[r]);
    }
  }
}

// ============ k3: depthwise conv3x3 + GELU + W2; channel quarter per wave, LDS reduce ============
__global__ __launch_bounds__(256,4) void k3_conv_ffn2(
  const unsigned short* __restrict__ g_h,
  const unsigned short* __restrict__ zrow,
  const float* __restrict__ dwp, const float* __restrict__ dwb,
  const float* __restrict__ b2,
  const unsigned short* __restrict__ wf,
  const unsigned short* __restrict__ g_txb, float* __restrict__ out)
{
  __shared__ unsigned short tiles[4][4096];
  const int t = threadIdx.x, wid = t>>6, l = t&63;
  const int l15 = l&15, lg = l>>4;
  unsigned short* tile = tiles[wid];
  // block = one 64-token strip; wave = one channel quarter (i = wid)
  const int strip = (blockIdx.x & 7)*512 + (blockIdx.x >> 3);   // XCD-chunked remap
  const int tok0 = strip*64;
  const int img  = tok0>>14;
  const int y    = (tok0>>7)&127;
  const int x0   = tok0&127;
  const bool okm = (y>0), okp = (y<127);
  const int p    = lg;
  const int ch   = l15;
  const int i    = wid;

  f32x4 oacc[4][4];   // [ntc][mtk] — partial (this wave's K=64 slice)
  #pragma unroll
  for (int a=0;a<4;++a)
    #pragma unroll
    for (int b=0;b<4;++b) oacc[a][b] = (f32x4){0.f,0.f,0.f,0.f};

  const size_t base = ((size_t)(img*128+y)*HPITCH + x0 + p*16)*256;

  // gelu constants with log2(e) folded in: g = a / (1 + exp2(a*(C0 + C1*a^2)))
  const f32x4 kC0 = {-2.3022082f,-2.3022082f,-2.3022082f,-2.3022082f};
  const f32x4 kC1 = {-0.1029432f,-0.1029432f,-0.1029432f,-0.1029432f};
  const f32x4 kOne = {1.f,1.f,1.f,1.f};

  const int f0 = i*64 + ch*4;
  f32x4 cw4[9];
  #pragma unroll
  for (int j=0;j<9;++j)
    cw4[j] = *reinterpret_cast<const f32x4*>(&dwp[(i*16+ch)*36 + j*4]);
  float4 cb4 = *reinterpret_cast<const float4*>(&dwb[f0]);
  f32x4 cbv = {cb4.x, cb4.y, cb4.z, cb4.w};

  const unsigned short* rB = g_h + base + f0;
  const unsigned short* rA = okm ? (rB - HROW) : (zrow + f0);
  const unsigned short* rC = okp ? (rB + HROW) : (zrow + f0);

  auto ldx = [](const unsigned short* pp, int o) -> f32x4 {
    uint2 q = *reinterpret_cast<const uint2*>(pp + o*256);
    return bfcvt4(q);
  };

  // 2-ahead rotation (round-0 structure, packed f32x4 math)
  f32x4 pA=ldx(rA,0), pB=ldx(rB,0), pC=ldx(rC,0);
  f32x4 cA=ldx(rA,1), cB=ldx(rB,1), cC=ldx(rC,1);
  #pragma unroll 4
  for (int s=0; s<16; ++s){
    f32x4 nA=ldx(rA,s+2), nB=ldx(rB,s+2), nC=ldx(rC,s+2);
    f32x4 a = cbv;
    a += cw4[0]*pA; a += cw4[1]*cA; a += cw4[2]*nA;
    a += cw4[3]*pB; a += cw4[4]*cB; a += cw4[5]*nB;
    a += cw4[6]*pC; a += cw4[7]*cC; a += cw4[8]*nC;
    f32x4 u = a*a;
    f32x4 w = u*kC1 + kC0;
    f32x4 arg = a*w;
    f32x4 e;
    e[0]=__builtin_amdgcn_exp2f(arg[0]); e[1]=__builtin_amdgcn_exp2f(arg[1]);
    e[2]=__builtin_amdgcn_exp2f(arg[2]); e[3]=__builtin_amdgcn_exp2f(arg[3]);
    f32x4 den = e + kOne;
    f32x4 rc;
    rc[0]=__builtin_amdgcn_rcpf(den[0]); rc[1]=__builtin_amdgcn_rcpf(den[1]);
    rc[2]=__builtin_amdgcn_rcpf(den[2]); rc[3]=__builtin_amdgcn_rcpf(den[3]);
    f32x4 g = a*rc;
    unsigned lo, hi;
    asm("v_cvt_pk_bf16_f32 %0, %1, %2" : "=v"(lo) : "v"(g[0]), "v"(g[1]));
    asm("v_cvt_pk_bf16_f32 %0, %1, %2" : "=v"(hi) : "v"(g[2]), "v"(g[3]));
    uint2 pk = { lo, hi };
    int row = p*16 + s;
    *reinterpret_cast<uint2*>(&tile[row*64 + ((ch*4) ^ ((row&7)<<3))]) = pk;
    pA=cA; pB=cB; pC=cC; cA=nA; cB=nB; cC=nC;
  }

  bf16x8 W2F[8];
  #pragma unroll
  for (int q=0;q<8;++q){
    int ntc = q>>1, cks = q&1;
    W2F[q] = ldfrag_g(wf + 32768 + (ntc*8 + i*2 + cks)*512 + l*8);
  }
  #pragma unroll
  for (int mtk=0; mtk<4; ++mtk){
    int row = mtk*16 + l15;
    int sw = (row&7)<<3;
    bf16x8 fb0 = __builtin_bit_cast(bf16x8, *reinterpret_cast<const u16x8*>(tile + row*64 + ((     lg*8) ^ sw)));
    bf16x8 fb1 = __builtin_bit_cast(bf16x8, *reinterpret_cast<const u16x8*>(tile + row*64 + ((32 + lg*8) ^ sw)));
    #pragma unroll
    for (int ntc=0;ntc<4;++ntc){
      oacc[ntc][mtk] = mfma16(W2F[ntc*2+0], fb0, oacc[ntc][mtk]);
      oacc[ntc][mtk] = mfma16(W2F[ntc*2+1], fb1, oacc[ntc][mtk]);
    }
  }

  // ---- staged cross-wave reduction of oacc into f32 LDS (reuses dead h-tiles) ----
  float* red = reinterpret_cast<float*>(&tiles[0][0]);   // 64 x 68 f32 = 17.4 KB < 32 KB
  __syncthreads();
  #define ORED(OP) \
    _Pragma("unroll") for (int ntc=0;ntc<4;++ntc) \
    _Pragma("unroll") for (int mtk=0;mtk<4;++mtk){ \
      f32x4* pr = reinterpret_cast<f32x4*>(&red[(mtk*16+l15)*68 + ntc*16 + lg*4]); \
      *pr OP oacc[ntc][mtk]; }
  if (wid==0){ ORED(=)  } __syncthreads();
  if (wid==1){ ORED(+=) } __syncthreads();
  if (wid==2){ ORED(+=) } __syncthreads();
  if (wid==3){ ORED(+=) } __syncthreads();
  #undef ORED

  // ---- cooperative vector epilogue: 4 x float4 per thread ----
  #pragma unroll
  for (int kk=0; kk<4; ++kk){
    int lin = kk*256 + t;
    int tok = lin>>4;
    int c4  = (lin&15)*4;
    float4 rv  = *reinterpret_cast<const float4*>(&red[tok*68 + c4]);
    float4 b2q = *reinterpret_cast<const float4*>(&b2[c4]);
    const size_t rowoff = (size_t)(tok0 + tok)*64 + c4;
    u16x4v tq = *reinterpret_cast<const u16x4v*>(&g_txb[rowoff]);
    float4 o;
    o.x = rv.x + b2q.x + bf2f(tq[0]);
    o.y = rv.y + b2q.y + bf2f(tq[1]);
    o.z = rv.z + b2q.z + bf2f(tq[2]);
    o.w = rv.w + b2q.w + bf2f(tq[3]);
    *reinterpret_cast<float4*>(&out[rowoff]) = o;
  }
}

extern "C" void kernel_launch(void* const* d_in, const int* in_sizes, int n_in,
                              void* d_out, int out_size, void* d_ws, size_t ws_size,
                              hipStream_t stream)
{
  const float* x  =(const float*)d_in[0];
  const float* g1 =(const float*)d_in[3];
  const float* be1=(const float*)d_in[4];
  const float* Wk =(const float*)d_in[5];
  const float* bk =(const float*)d_in[6];
  const float* Wq =(const float*)d_in[7];
  const float* bq =(const float*)d_in[8];
  const float* Wv =(const float*)d_in[9];
  const float* bv =(const float*)d_in[10];
  const float* Wr =(const float*)d_in[11];
  const float* br =(const float*)d_in[12];
  const float* g2 =(const float*)d_in[13];
  const float* be2=(const float*)d_in[14];
  const float* W1 =(const float*)d_in[15];
  const float* b1 =(const float*)d_in[16];
  const float* dww=(const float*)d_in[17];
  const float* dwb=(const float*)d_in[18];
  const float* W2 =(const float*)d_in[19];
  const float* b2 =(const float*)d_in[20];
  float* outp = (float*)d_out;
  char* ws = (char*)d_ws;

  unsigned short* wfb    = (unsigned short*)ws;                 // 96KB
  unsigned short* ctxWrF = (unsigned short*)(ws + 98304);       // 128KB
  float* g_sump = (float*)(ws + 229376);                        // 128KB
  float* g_part = (float*)(ws + 393216);                        // 8MB
  unsigned short* g_txb = (unsigned short*)(ws + 16777216);     // 32MB bf16
  unsigned short* g_h   = (unsigned short*)(ws + 50331648);     // 136.3MB padded bf16
  unsigned short* zr    = (unsigned short*)(ws + 186646528);    // 65KB zero row
  float* dwp            = (float*)(ws + 186712064);             // 12KB repacked taps

  hipLaunchKernelGGL(k0_wfrag, dim3(97), dim3(64), 0, stream, Wk, Wq, Wv, Wr, W1, W2, dww, dwp, wfb);
  hipLaunchKernelGGL(zhalo, dim3(2113), dim3(256), 0, stream, (unsigned*)g_h, (unsigned*)zr);
  hipLaunchKernelGGL(k1_ctx, dim3(512), dim3(256), 0, stream, x, g1, be1, bk, bv, wfb, g_part, g_sump);
  hipLaunchKernelGGL(k15_ctxwr, dim3(16), dim3(512), 0, stream, g_part, g_sump, Wr, ctxWrF);
  hipLaunchKernelGGL(k2_attn_ffn1, dim3(1024), dim3(256), 0, stream,
                     x, g1, be1, bq, br, g2, be2, b1, wfb, ctxWrF, g_txb, g_h);
  hipLaunchKernelGGL(k3_conv_ffn2, dim3(4096), dim3(256), 0, stream,
                     g_h, zr, dwp, dwb, b2, wfb, g_txb, outp);
}

// Round 3
// 251.420 us; speedup vs baseline: 1.0507x; 1.0507x over previous
//
#include <hip/hip_runtime.h>
#include <math.h>

typedef __bf16 bf16x8 __attribute__((ext_vector_type(8)));
typedef float f32x4 __attribute__((ext_vector_type(4)));
typedef unsigned short u16x8 __attribute__((ext_vector_type(8)));
typedef unsigned short u16x4v __attribute__((ext_vector_type(4)));

constexpr int NIMG = 16384;   // H*W
constexpr int HPITCH = 130;   // padded row pitch (tokens) for g_h
constexpr int HROW = HPITCH*256; // shorts per padded image row

__device__ __forceinline__ unsigned short f2bf(float f){
  unsigned u = __builtin_bit_cast(unsigned, f);
  u += 0x7fffu + ((u>>16)&1u);
  return (unsigned short)(u>>16);
}
__device__ __forceinline__ unsigned pack2(float a, float b){
  return (unsigned)f2bf(a) | ((unsigned)f2bf(b)<<16);
}
__device__ __forceinline__ float bf2f(unsigned short h){
  unsigned u = ((unsigned)h)<<16;
  return __builtin_bit_cast(float, u);
}
__device__ __forceinline__ bf16x8 ldfrag_g(const unsigned short* p){
  u16x8 v = *reinterpret_cast<const u16x8*>(p);
  return __builtin_bit_cast(bf16x8, v);
}
__device__ __forceinline__ f32x4 mfma16(bf16x8 a, bf16x8 b, f32x4 c){
  return __builtin_amdgcn_mfma_f32_16x16x32_bf16(a, b, c, 0, 0, 0);
}
__device__ __forceinline__ f32x4 bfcvt4(uint2 q){
  f32x4 r;
  r[0] = __builtin_bit_cast(float, q.x << 16);
  r[1] = __builtin_bit_cast(float, q.x & 0xffff0000u);
  r[2] = __builtin_bit_cast(float, q.y << 16);
  r[3] = __builtin_bit_cast(float, q.y & 0xffff0000u);
  return r;
}

// ============ k0: weights fp32 -> bf16 MFMA fragment layout (+ tap repack) ============
__global__ __launch_bounds__(64) void k0_wfrag(
  const float* __restrict__ Wk, const float* __restrict__ Wq,
  const float* __restrict__ Wv, const float* __restrict__ Wr,
  const float* __restrict__ W1, const float* __restrict__ W2,
  const float* __restrict__ dww, float* __restrict__ dwp,
  unsigned short* __restrict__ wf)
{
  const int bid = blockIdx.x, l = threadIdx.x;
  if (bid == 96){
    // repack taps: dwp[group g=0..63][tap j=0..8][ch c=0..3] ; channel f = g*4+c
    #pragma unroll
    for (int c=0;c<4;++c){
      int f = l*4 + c;
      #pragma unroll
      for (int j=0;j<9;++j) dwp[l*36 + j*4 + c] = dww[f*9+j];
    }
    return;
  }
  const float* src; int K, nt, ks; unsigned short* dst;
  if (bid < 32){
    int w = bid>>3, f = bid&7;
    src = (w==0)?Wk:(w==1)?Wq:(w==2)?Wv:Wr;
    K = 64; nt = f>>1; ks = f&1;
    dst = wf + w*4096 + f*512;
  } else if (bid < 64){
    int f = bid-32; src = W1; K = 64; nt = f>>1; ks = f&1;
    dst = wf + 16384 + f*512;
  } else {
    int f = bid-64; src = W2; K = 256; nt = f>>3; ks = f&7;
    dst = wf + 32768 + f*512;
  }
  u16x8 v;
  #pragma unroll
  for (int j=0;j<8;++j){
    int k = ks*32 + (l>>4)*8 + j;
    int n = nt*16 + (l&15);
    v[j] = f2bf(src[n*K + k]);
  }
  *reinterpret_cast<u16x8*>(dst + l*8) = v;
}

// ============ zhalo: zero g_h halo columns + shared zero-row ============
__global__ __launch_bounds__(256) void zhalo(unsigned* __restrict__ gh, unsigned* __restrict__ zr){
  int idx = blockIdx.x*256 + threadIdx.x;
  if (idx < 524288){
    int ch2 = idx & 127;
    int pos = idx >> 7;
    int side = pos & 1, row = pos >> 1;
    gh[(size_t)(row*HPITCH + side*(HPITCH-1))*128 + ch2] = 0;
  } else {
    int j = idx - 524288;
    if (j < HROW/2) zr[j] = 0;
  }
}

// ============ k1: LN1 + K/V proj (MFMA) + ctx accumulation (MFMA, LDS-transpose) ============
__global__ __launch_bounds__(256,2) void k1_ctx(
  const float* __restrict__ x, const float* __restrict__ g1, const float* __restrict__ be1,
  const float* __restrict__ bk, const float* __restrict__ bv,
  const unsigned short* __restrict__ wf,
  float* __restrict__ g_part, float* __restrict__ g_sump)
{
  __shared__ unsigned short tiles[4][4096];
  __shared__ float ctx_l[64*68];
  __shared__ float ssum_l[4][64];
  const int t = threadIdx.x, wid = t>>6, l = t&63;
  const int lg = l>>4, l15 = l&15;
  unsigned short* tile = tiles[wid];
  const int tok0 = blockIdx.x*512 + wid*128;

  bf16x8 WkF[8], WvF[8];
  #pragma unroll
  for (int f=0; f<8; ++f){
    WkF[f] = ldfrag_g(wf +    0 + f*512 + l*8);
    WvF[f] = ldfrag_g(wf + 8192 + f*512 + l*8);
  }
  float4 g1v  = *reinterpret_cast<const float4*>(&g1[l15*4]);
  float4 be1v = *reinterpret_cast<const float4*>(&be1[l15*4]);
  float bkv[4], bvv[4];
  #pragma unroll
  for (int ct=0; ct<4; ++ct){ bkv[ct]=bk[ct*16+l15]; bvv[ct]=bv[ct*16+l15]; }

  f32x4 acc[4][4];
  #pragma unroll
  for (int a=0;a<4;++a)
    #pragma unroll
    for (int b=0;b<4;++b) acc[a][b] = (f32x4){0.f,0.f,0.f,0.f};
  float sume[4] = {0.f,0.f,0.f,0.f};

  for (int tb=0; tb<2; ++tb){
    const int tbase = tok0 + tb*64;
    #pragma unroll
    for (int it=0; it<16; ++it){
      int row = it*4 + lg;
      float4 xv = *reinterpret_cast<const float4*>(&x[(size_t)(tbase+row)*64 + l15*4]);
      float s1 = xv.x+xv.y+xv.z+xv.w;
      float s2 = xv.x*xv.x + xv.y*xv.y + xv.z*xv.z + xv.w*xv.w;
      #pragma unroll
      for (int off=1; off<16; off<<=1){ s1 += __shfl_xor(s1,off,64); s2 += __shfl_xor(s2,off,64); }
      float mu = s1*(1.f/64.f);
      float rs = rsqrtf(s2*(1.f/64.f) - mu*mu + 1e-5f);
      uint2 pk = { pack2((xv.x-mu)*rs*g1v.x + be1v.x, (xv.y-mu)*rs*g1v.y + be1v.y),
                   pack2((xv.z-mu)*rs*g1v.z + be1v.z, (xv.w-mu)*rs*g1v.w + be1v.w) };
      *reinterpret_cast<uint2*>(&tile[row*64 + ((l15*4) ^ ((row&7)<<3))]) = pk;
    }
    bf16x8 aF[4][2];
    #pragma unroll
    for (int mt=0;mt<4;++mt){
      int row = mt*16+l15, sw=(row&7)<<3, ab=row*64;
      aF[mt][0] = __builtin_bit_cast(bf16x8, *reinterpret_cast<const u16x8*>(tile+ab+((     lg*8)^sw)));
      aF[mt][1] = __builtin_bit_cast(bf16x8, *reinterpret_cast<const u16x8*>(tile+ab+((32 + lg*8)^sw)));
    }
    #pragma unroll
    for (int half=0; half<2; ++half){
      #pragma unroll
      for (int m2=0;m2<2;++m2){
        const int mt = half*2+m2;
        #pragma unroll
        for (int ct=0;ct<4;++ct){
          f32x4 z = {0.f,0.f,0.f,0.f};
          z = mfma16(aF[mt][0], WkF[ct*2+0], z);
          z = mfma16(aF[mt][1], WkF[ct*2+1], z);
          float e0=__expf(z[0]+bkv[ct]), e1=__expf(z[1]+bkv[ct]);
          float e2=__expf(z[2]+bkv[ct]), e3=__expf(z[3]+bkv[ct]);
          sume[ct] += (e0+e1)+(e2+e3);
          const int c = ct*16+l15, sw = (c&7)<<3;
          const int cb = m2*16+lg*4;
          uint2 pe = { pack2(e0,e1), pack2(e2,e3) };
          *reinterpret_cast<uint2*>(&tile[c*64 + (cb ^ sw)]) = pe;
          f32x4 w = {0.f,0.f,0.f,0.f};
          w = mfma16(aF[mt][0], WvF[ct*2+0], w);
          w = mfma16(aF[mt][1], WvF[ct*2+1], w);
          uint2 pv = { pack2(w[0]+bvv[ct], w[1]+bvv[ct]), pack2(w[2]+bvv[ct], w[3]+bvv[ct]) };
          *reinterpret_cast<uint2*>(&tile[c*64 + ((32+cb) ^ sw)]) = pv;
        }
      }
      bf16x8 eA[4], vB[4];
      #pragma unroll
      for (int cm=0;cm<4;++cm){
        int row = cm*16+l15, sw=(row&7)<<3;
        eA[cm] = __builtin_bit_cast(bf16x8, *reinterpret_cast<const u16x8*>(tile + row*64 + ((     lg*8)^sw)));
        vB[cm] = __builtin_bit_cast(bf16x8, *reinterpret_cast<const u16x8*>(tile + row*64 + ((32 + lg*8)^sw)));
      }
      #pragma unroll
      for (int cm=0; cm<4; ++cm)
        #pragma unroll
        for (int jn=0; jn<4; ++jn)
          acc[cm][jn] = mfma16(eA[cm], vB[jn], acc[cm][jn]);
    }
  }
  #pragma unroll
  for (int ct=0; ct<4; ++ct){
    float s = sume[ct];
    s += __shfl_xor(s,16,64); s += __shfl_xor(s,32,64);
    if (lg==0) ssum_l[wid][ct*16+l15] = s;
  }
  #define CTX_RED(OP) \
    _Pragma("unroll") for (int cm=0;cm<4;++cm) \
    _Pragma("unroll") for (int jn=0;jn<4;++jn) \
    _Pragma("unroll") for (int r=0;r<4;++r) \
      ctx_l[(cm*16+lg*4+r)*68 + jn*16+l15] OP acc[cm][jn][r];
  if (wid==0){ CTX_RED(=) }  __syncthreads();
  if (wid==1){ CTX_RED(+=) } __syncthreads();
  if (wid==2){ CTX_RED(+=) } __syncthreads();
  if (wid==3){ CTX_RED(+=) } __syncthreads();
  #undef CTX_RED
  for (int i=t; i<4096; i+=256)
    g_part[(size_t)blockIdx.x*4096 + i] = ctx_l[(i>>6)*68 + (i&63)];
  if (t<64)
    g_sump[blockIdx.x*64 + t] = ssum_l[0][t]+ssum_l[1][t]+ssum_l[2][t]+ssum_l[3][t];
}

// ============ k15: reduce partials; ctxWr = (ctx_norm @ Wr^T) -> bf16 frags ============
__global__ __launch_bounds__(512) void k15_ctxwr(
  const float* __restrict__ g_part, const float* __restrict__ g_sump,
  const float* __restrict__ Wr, unsigned short* __restrict__ ctxWrF)
{
  __shared__ float sctx[4096];
  __shared__ float sWr[4096];
  __shared__ float sinv[64];
  const int b = blockIdx.x, t = threadIdx.x;
  if (t<64){
    float s=0.f;
    #pragma unroll 8
    for (int p=0;p<32;++p) s += g_sump[(b*32+p)*64 + t];
    sinv[t] = 1.f/s;
  }
  for (int idx=t; idx<4096; idx+=512){
    float s=0.f;
    #pragma unroll 8
    for (int p=0;p<32;++p) s += g_part[(size_t)(b*32+p)*4096 + idx];
    sctx[idx] = s;
  }
  __syncthreads();
  {
    int c = t>>3, d0 = (t&7)*8;
    float invc = sinv[c];
    #pragma unroll
    for (int dd=0; dd<8; ++dd){
      int d = d0+dd; float s = 0.f;
      #pragma unroll
      for (int v=0; v<64; ++v) s += sctx[c*64+v]*Wr[d*64+v];
      sWr[c*64+d] = s*invc;
    }
  }
  __syncthreads();
  {
    int f = t>>6, l = t&63, nt = f>>1, ks = f&1;
    u16x8 v;
    #pragma unroll
    for (int j=0;j<8;++j){
      int k = ks*32 + (l>>4)*8 + j;
      int n = nt*16 + (l&15);
      v[j] = f2bf(sWr[k*64+n]);
    }
    *reinterpret_cast<u16x8*>(ctxWrF + b*4096 + f*512 + l*8) = v;
  }
}

// ============ k2: LN1 + q-softmax + attn + residual + LN2 + W1 (nt2-outer phase B) ============
__global__ __launch_bounds__(256,2) void k2_attn_ffn1(
  const float* __restrict__ x,
  const float* __restrict__ g1, const float* __restrict__ be1,
  const float* __restrict__ bq, const float* __restrict__ br,
  const float* __restrict__ g2, const float* __restrict__ be2,
  const float* __restrict__ b1,
  const unsigned short* __restrict__ wf,
  const unsigned short* __restrict__ ctxWrF,
  unsigned short* __restrict__ g_txb, unsigned short* __restrict__ g_h)
{
  __shared__ unsigned short tiles[4][4096];
  const int t = threadIdx.x, wid = t>>6, l = t&63;
  const int l15 = l&15, lg = l>>4;
  unsigned short* tile = tiles[wid];
  const int tok0 = (blockIdx.x*4 + wid)*64;
  const int img  = blockIdx.x>>6;
  const int yrow = (tok0>>7)&127;
  const int xb   = tok0&127;
  const size_t hbase = ((size_t)(img*128 + yrow)*HPITCH + 1 + xb)*256;

  bf16x8 WqF[8], CWF[8];
  #pragma unroll
  for (int f=0; f<8; ++f){
    WqF[f] = ldfrag_g(wf + 4096 + f*512 + l*8);
    CWF[f] = ldfrag_g(ctxWrF + img*4096 + f*512 + l*8);
  }
  float4 g1v  = *reinterpret_cast<const float4*>(&g1[l15*4]);
  float4 be1v = *reinterpret_cast<const float4*>(&be1[l15*4]);
  float bqv[4], brv[4], g2v[4], be2v[4];
  #pragma unroll
  for (int nt=0; nt<4; ++nt){
    bqv[nt]=bq[nt*16+l15]; brv[nt]=br[nt*16+l15];
    g2v[nt]=g2[nt*16+l15]; be2v[nt]=be2[nt*16+l15];
  }
  float b1v[16];
  #pragma unroll
  for (int i=0;i<16;++i) b1v[i]=b1[i*16+l15];

  // ---- LN1 -> swizzled bf16 tile ----
  #pragma unroll
  for (int it=0; it<16; ++it){
    int row = it*4 + lg;
    float4 xv = *reinterpret_cast<const float4*>(&x[(size_t)(tok0+row)*64 + l15*4]);
    float s1 = xv.x+xv.y+xv.z+xv.w;
    float s2 = xv.x*xv.x + xv.y*xv.y + xv.z*xv.z + xv.w*xv.w;
    #pragma unroll
    for (int off=1; off<16; off<<=1){ s1 += __shfl_xor(s1,off,64); s2 += __shfl_xor(s2,off,64); }
    float mu = s1*(1.f/64.f);
    float rs = rsqrtf(s2*(1.f/64.f) - mu*mu + 1e-5f);
    uint2 pk = { pack2((xv.x-mu)*rs*g1v.x + be1v.x, (xv.y-mu)*rs*g1v.y + be1v.y),
                 pack2((xv.z-mu)*rs*g1v.z + be1v.z, (xv.w-mu)*rs*g1v.w + be1v.w) };
    *reinterpret_cast<uint2*>(&tile[row*64 + ((l15*4) ^ ((row&7)<<3))]) = pk;
  }

  // ---- phase A: per m-tile attn chain; leaves n2 in the tile ----
  for (int mt=0; mt<4; ++mt){
    const int arow = mt*16 + l15;
    const int asw  = (arow&7)<<3;
    const int abase= arow*64;
    bf16x8 a0 = __builtin_bit_cast(bf16x8, *reinterpret_cast<const u16x8*>(tile + abase + ((     lg*8) ^ asw)));
    bf16x8 a1 = __builtin_bit_cast(bf16x8, *reinterpret_cast<const u16x8*>(tile + abase + ((32 + lg*8) ^ asw)));
    f32x4 qa[4];
    #pragma unroll
    for (int nt=0; nt<4; ++nt){
      f32x4 z = {0.f,0.f,0.f,0.f};
      z = mfma16(a0, WqF[nt*2+0], z);
      z = mfma16(a1, WqF[nt*2+1], z);
      qa[nt] = z;
    }
    #pragma unroll
    for (int nt=0; nt<4; ++nt)
      #pragma unroll
      for (int r=0; r<4; ++r) qa[nt][r] += bqv[nt];
    float mx[4];
    #pragma unroll
    for (int r=0;r<4;++r) mx[r] = fmaxf(fmaxf(qa[0][r],qa[1][r]), fmaxf(qa[2][r],qa[3][r]));
    #pragma unroll
    for (int off=1; off<16; off<<=1)
      #pragma unroll
      for (int r=0;r<4;++r) mx[r] = fmaxf(mx[r], __shfl_xor(mx[r], off, 64));
    float sm[4] = {0.f,0.f,0.f,0.f};
    #pragma unroll
    for (int nt=0;nt<4;++nt)
      #pragma unroll
      for (int r=0;r<4;++r){ float e = __expf(qa[nt][r]-mx[r]); qa[nt][r]=e; sm[r]+=e; }
    #pragma unroll
    for (int off=1; off<16; off<<=1)
      #pragma unroll
      for (int r=0;r<4;++r) sm[r] += __shfl_xor(sm[r], off, 64);
    float inv[4];
    #pragma unroll
    for (int r=0;r<4;++r) inv[r] = 1.f/sm[r];
    #pragma unroll
    for (int nt=0;nt<4;++nt)
      #pragma unroll
      for (int r=0;r<4;++r){
        int row = mt*16 + lg*4 + r, col = nt*16 + l15;
        tile[row*64 + (col ^ ((row&7)<<3))] = f2bf(qa[nt][r]*inv[r]);
      }
    bf16x8 p0 = __builtin_bit_cast(bf16x8, *reinterpret_cast<const u16x8*>(tile + abase + ((     lg*8) ^ asw)));
    bf16x8 p1 = __builtin_bit_cast(bf16x8, *reinterpret_cast<const u16x8*>(tile + abase + ((32 + lg*8) ^ asw)));
    f32x4 ao[4];
    #pragma unroll
    for (int nt=0; nt<4; ++nt){
      f32x4 z = {0.f,0.f,0.f,0.f};
      z = mfma16(p0, CWF[nt*2+0], z);
      z = mfma16(p1, CWF[nt*2+1], z);
      ao[nt] = z;
    }
    float txv[4][4];
    float s1v[4] = {0.f,0.f,0.f,0.f}, s2v[4] = {0.f,0.f,0.f,0.f};
    #pragma unroll
    for (int nt=0;nt<4;++nt)
      #pragma unroll
      for (int r=0;r<4;++r){
        size_t row = (size_t)(tok0 + mt*16 + lg*4 + r);
        float v = ao[nt][r] + brv[nt] + x[row*64 + nt*16+l15];
        g_txb[row*64 + nt*16+l15] = f2bf(v);
        txv[nt][r] = v; s1v[r] += v; s2v[r] += v*v;
      }
    #pragma unroll
    for (int off=1; off<16; off<<=1)
      #pragma unroll
      for (int r=0;r<4;++r){ s1v[r] += __shfl_xor(s1v[r], off, 64); s2v[r] += __shfl_xor(s2v[r], off, 64); }
    #pragma unroll
    for (int r=0;r<4;++r){
      float mu2 = s1v[r]*(1.f/64.f);
      float rs  = rsqrtf(s2v[r]*(1.f/64.f) - mu2*mu2 + 1e-5f);
      s1v[r] = mu2; s2v[r] = rs;
    }
    #pragma unroll
    for (int nt=0;nt<4;++nt)
      #pragma unroll
      for (int r=0;r<4;++r){
        int row = mt*16 + lg*4 + r, col = nt*16 + l15;
        float n2 = (txv[nt][r]-s1v[r])*s2v[r]*g2v[nt] + be2v[nt];
        tile[row*64 + (col ^ ((row&7)<<3))] = f2bf(n2);
      }
  }

  // ---- phase B: h = n2 @ W1^T + b1 (nt2 outer: each W1 frag loaded ONCE) ----
  #pragma unroll 2
  for (int nt2=0; nt2<16; ++nt2){
    bf16x8 w0 = ldfrag_g(wf + 16384 + (nt2*2+0)*512 + l*8);
    bf16x8 w1 = ldfrag_g(wf + 16384 + (nt2*2+1)*512 + l*8);
    float bb = b1v[nt2];
    #pragma unroll
    for (int mt=0; mt<4; ++mt){
      const int arow = mt*16 + l15;
      const int asw  = (arow&7)<<3;
      const int abase= arow*64;
      bf16x8 n20 = __builtin_bit_cast(bf16x8, *reinterpret_cast<const u16x8*>(tile + abase + ((     lg*8) ^ asw)));
      bf16x8 n21 = __builtin_bit_cast(bf16x8, *reinterpret_cast<const u16x8*>(tile + abase + ((32 + lg*8) ^ asw)));
      f32x4 h = {bb,bb,bb,bb};
      h = mfma16(n20, w0, h);
      h = mfma16(n21, w1, h);
      #pragma unroll
      for (int r=0;r<4;++r)
        g_h[hbase + (size_t)(mt*16+lg*4+r)*256 + nt2*16 + l15] = f2bf(h[r]);
    }
  }
}

// ============ k3: depthwise conv3x3 + GELU + W2 ============
// wave = conv-channel-quarter (wid), then OUTPUT-quarter (wid) for the W2 MFMA:
// no cross-wave accumulator reduce, exactly ONE barrier. Conv loads pipelined
// 3 iterations ahead via raw uint2 rotation (convert 2 iters before use).
__global__ __launch_bounds__(256,4) void k3_conv_ffn2(
  const unsigned short* __restrict__ g_h,
  const unsigned short* __restrict__ zrow,
  const float* __restrict__ dwp, const float* __restrict__ dwb,
  const float* __restrict__ b2,
  const unsigned short* __restrict__ wf,
  const unsigned short* __restrict__ g_txb, float* __restrict__ out)
{
  __shared__ unsigned short tiles[4][4096];
  const int t = threadIdx.x, wid = t>>6, l = t&63;
  const int l15 = l&15, lg = l>>4;
  unsigned short* tile = tiles[wid];
  // block = one 64-token strip; conv: wave wid owns channel quarter wid
  const int strip = (blockIdx.x & 7)*512 + (blockIdx.x >> 3);   // XCD-chunked remap
  const int tok0 = strip*64;
  const int img  = tok0>>14;
  const int y    = (tok0>>7)&127;
  const int x0   = tok0&127;
  const bool okm = (y>0), okp = (y<127);
  const int p    = lg;
  const int ch   = l15;

  // gelu constants with log2(e) folded in: g = a / (1 + exp2(a*(C0 + C1*a^2)))
  const f32x4 kC0 = {-2.3022082f,-2.3022082f,-2.3022082f,-2.3022082f};
  const f32x4 kC1 = {-0.1029432f,-0.1029432f,-0.1029432f,-0.1029432f};
  const f32x4 kOne = {1.f,1.f,1.f,1.f};

  const int f0 = wid*64 + ch*4;
  f32x4 cw4[9];
  #pragma unroll
  for (int j=0;j<9;++j)
    cw4[j] = *reinterpret_cast<const f32x4*>(&dwp[(wid*16+ch)*36 + j*4]);
  float4 cb4 = *reinterpret_cast<const float4*>(&dwb[f0]);
  f32x4 cbv = {cb4.x, cb4.y, cb4.z, cb4.w};

  const size_t base = ((size_t)(img*128+y)*HPITCH + x0 + p*16)*256;
  const unsigned short* rB = g_h + base + f0;
  const unsigned short* rA = okm ? (rB - HROW) : (zrow + f0);
  const unsigned short* rC = okp ? (rB + HROW) : (zrow + f0);

  auto ldr = [](const unsigned short* pp, int o) -> uint2 {
    return *reinterpret_cast<const uint2*>(pp + o*256);
  };

  // prologue: positions 0,1 converted; 2,3,4 raw in flight
  f32x4 PA=bfcvt4(ldr(rA,0)), PB=bfcvt4(ldr(rB,0)), PC=bfcvt4(ldr(rC,0));
  f32x4 CA=bfcvt4(ldr(rA,1)), CB=bfcvt4(ldr(rB,1)), CC=bfcvt4(ldr(rC,1));
  uint2 r2A=ldr(rA,2), r2B=ldr(rB,2), r2C=ldr(rC,2);
  uint2 r3A=ldr(rA,3), r3B=ldr(rB,3), r3C=ldr(rC,3);
  uint2 r4A=ldr(rA,4), r4B=ldr(rB,4), r4C=ldr(rC,4);

  #pragma unroll 4
  for (int s=0; s<16; ++s){
    // issue loads for position s+5 (clamped; tail re-loads 17 harmlessly)
    const int o = (s<13) ? (s+5) : 17;
    uint2 r5A=ldr(rA,o), r5B=ldr(rB,o), r5C=ldr(rC,o);
    // convert position s+2 (loaded 3 iterations ago)
    f32x4 NA=bfcvt4(r2A), NB=bfcvt4(r2B), NC=bfcvt4(r2C);
    f32x4 a = cbv;
    a += cw4[0]*PA; a += cw4[1]*CA; a += cw4[2]*NA;
    a += cw4[3]*PB; a += cw4[4]*CB; a += cw4[5]*NB;
    a += cw4[6]*PC; a += cw4[7]*CC; a += cw4[8]*NC;
    f32x4 u = a*a;
    f32x4 w = u*kC1 + kC0;
    f32x4 arg = a*w;
    f32x4 e;
    e[0]=__builtin_amdgcn_exp2f(arg[0]); e[1]=__builtin_amdgcn_exp2f(arg[1]);
    e[2]=__builtin_amdgcn_exp2f(arg[2]); e[3]=__builtin_amdgcn_exp2f(arg[3]);
    f32x4 den = e + kOne;
    f32x4 rc;
    rc[0]=__builtin_amdgcn_rcpf(den[0]); rc[1]=__builtin_amdgcn_rcpf(den[1]);
    rc[2]=__builtin_amdgcn_rcpf(den[2]); rc[3]=__builtin_amdgcn_rcpf(den[3]);
    f32x4 g = a*rc;
    unsigned lo, hi;
    asm("v_cvt_pk_bf16_f32 %0, %1, %2" : "=v"(lo) : "v"(g[0]), "v"(g[1]));
    asm("v_cvt_pk_bf16_f32 %0, %1, %2" : "=v"(hi) : "v"(g[2]), "v"(g[3]));
    uint2 pk = { lo, hi };
    int row = p*16 + s;
    *reinterpret_cast<uint2*>(&tile[row*64 + ((ch*4) ^ ((row&7)<<3))]) = pk;
    // rotate
    PA=CA; PB=CB; PC=CC; CA=NA; CB=NB; CC=NC;
    r2A=r3A; r2B=r3B; r2C=r3C;
    r3A=r4A; r3B=r4B; r3C=r4C;
    r4A=r5A; r4B=r5B; r4C=r5C;
  }

  // prefetch residual (epilogue) + W2 frags for OUTPUT quarter wid; latency
  // hides under the barrier + LDS reads.
  u16x4v tq[4];
  #pragma unroll
  for (int mtk=0;mtk<4;++mtk)
    tq[mtk] = *reinterpret_cast<const u16x4v*>(
        &g_txb[(size_t)(tok0 + mtk*16 + l15)*64 + wid*16 + lg*4]);
  bf16x8 W2F[8];
  #pragma unroll
  for (int q=0;q<8;++q){
    int i2 = q>>1, cks = q&1;
    W2F[q] = ldfrag_g(wf + 32768 + (wid*8 + i2*2 + cks)*512 + l*8);
  }

  __syncthreads();

  // W2 MFMA: wave wid computes OUTPUT quarter wid over all K=256
  // (reads all four conv tiles; no cross-wave reduce)
  f32x4 oacc[4];
  #pragma unroll
  for (int mtk=0;mtk<4;++mtk) oacc[mtk] = (f32x4){0.f,0.f,0.f,0.f};
  #pragma unroll
  for (int i=0;i<4;++i){
    const unsigned short* tp = tiles[i];
    #pragma unroll
    for (int mtk=0; mtk<4; ++mtk){
      int row = mtk*16 + l15;
      int sw = (row&7)<<3;
      bf16x8 fb0 = __builtin_bit_cast(bf16x8, *reinterpret_cast<const u16x8*>(tp + row*64 + ((     lg*8) ^ sw)));
      bf16x8 fb1 = __builtin_bit_cast(bf16x8, *reinterpret_cast<const u16x8*>(tp + row*64 + ((32 + lg*8) ^ sw)));
      oacc[mtk] = mfma16(W2F[i*2+0], fb0, oacc[mtk]);
      oacc[mtk] = mfma16(W2F[i*2+1], fb1, oacc[mtk]);
    }
  }

  // ---- vector epilogue: wave writes its output quarter ----
  float4 b2q = *reinterpret_cast<const float4*>(&b2[wid*16 + lg*4]);
  #pragma unroll
  for (int mtk=0;mtk<4;++mtk){
    const size_t off = (size_t)(tok0 + mtk*16 + l15)*64 + wid*16 + lg*4;
    float4 o;
    o.x = oacc[mtk][0] + b2q.x + bf2f(tq[mtk][0]);
    o.y = oacc[mtk][1] + b2q.y + bf2f(tq[mtk][1]);
    o.z = oacc[mtk][2] + b2q.z + bf2f(tq[mtk][2]);
    o.w = oacc[mtk][3] + b2q.w + bf2f(tq[mtk][3]);
    *reinterpret_cast<float4*>(&out[off]) = o;
  }
}

extern "C" void kernel_launch(void* const* d_in, const int* in_sizes, int n_in,
                              void* d_out, int out_size, void* d_ws, size_t ws_size,
                              hipStream_t stream)
{
  const float* x  =(const float*)d_in[0];
  const float* g1 =(const float*)d_in[3];
  const float* be1=(const float*)d_in[4];
  const float* Wk =(const float*)d_in[5];
  const float* bk =(const float*)d_in[6];
  const float* Wq =(const float*)d_in[7];
  const float* bq =(const float*)d_in[8];
  const float* Wv =(const float*)d_in[9];
  const float* bv =(const float*)d_in[10];
  const float* Wr =(const float*)d_in[11];
  const float* br =(const float*)d_in[12];
  const float* g2 =(const float*)d_in[13];
  const float* be2=(const float*)d_in[14];
  const float* W1 =(const float*)d_in[15];
  const float* b1 =(const float*)d_in[16];
  const float* dww=(const float*)d_in[17];
  const float* dwb=(const float*)d_in[18];
  const float* W2 =(const float*)d_in[19];
  const float* b2 =(const float*)d_in[20];
  float* outp = (float*)d_out;
  char* ws = (char*)d_ws;

  unsigned short* wfb    = (unsigned short*)ws;                 // 96KB
  unsigned short* ctxWrF = (unsigned short*)(ws + 98304);       // 128KB
  float* g_sump = (float*)(ws + 229376);                        // 128KB
  float* g_part = (float*)(ws + 393216);                        // 8MB
  unsigned short* g_txb = (unsigned short*)(ws + 16777216);     // 32MB bf16
  unsigned short* g_h   = (unsigned short*)(ws + 50331648);     // 136.3MB padded bf16
  unsigned short* zr    = (unsigned short*)(ws + 186646528);    // 65KB zero row
  float* dwp            = (float*)(ws + 186712064);             // 12KB repacked taps

  hipLaunchKernelGGL(k0_wfrag, dim3(97), dim3(64), 0, stream, Wk, Wq, Wv, Wr, W1, W2, dww, dwp, wfb);
  hipLaunchKernelGGL(zhalo, dim3(2113), dim3(256), 0, stream, (unsigned*)g_h, (unsigned*)zr);
  hipLaunchKernelGGL(k1_ctx, dim3(512), dim3(256), 0, stream, x, g1, be1, bk, bv, wfb, g_part, g_sump);
  hipLaunchKernelGGL(k15_ctxwr, dim3(16), dim3(512), 0, stream, g_part, g_sump, Wr, ctxWrF);
  hipLaunchKernelGGL(k2_attn_ffn1, dim3(1024), dim3(256), 0, stream,
                     x, g1, be1, bq, br, g2, be2, b1, wfb, ctxWrF, g_txb, g_h);
  hipLaunchKernelGGL(k3_conv_ffn2, dim3(4096), dim3(256), 0, stream,
                     g_h, zr, dwp, dwb, b2, wfb, g_txb, outp);
}

// Round 4
// 248.045 us; speedup vs baseline: 1.0650x; 1.0136x over previous
//
#include <hip/hip_runtime.h>
#include <math.h>

typedef __bf16 bf16x8 __attribute__((ext_vector_type(8)));
typedef float f32x4 __attribute__((ext_vector_type(4)));
typedef float f32x2 __attribute__((ext_vector_type(2)));
typedef unsigned short u16x8 __attribute__((ext_vector_type(8)));
typedef unsigned short u16x4v __attribute__((ext_vector_type(4)));

constexpr int NIMG = 16384;   // H*W
constexpr int HPITCH = 130;   // padded row pitch (tokens) for g_h
constexpr int HROW = HPITCH*256; // shorts per padded image row

__device__ __forceinline__ unsigned short f2bf(float f){
  unsigned u = __builtin_bit_cast(unsigned, f);
  u += 0x7fffu + ((u>>16)&1u);
  return (unsigned short)(u>>16);
}
__device__ __forceinline__ unsigned pack2(float a, float b){
  return (unsigned)f2bf(a) | ((unsigned)f2bf(b)<<16);
}
__device__ __forceinline__ float bf2f(unsigned short h){
  unsigned u = ((unsigned)h)<<16;
  return __builtin_bit_cast(float, u);
}
__device__ __forceinline__ bf16x8 ldfrag_g(const unsigned short* p){
  u16x8 v = *reinterpret_cast<const u16x8*>(p);
  return __builtin_bit_cast(bf16x8, v);
}
__device__ __forceinline__ f32x4 mfma16(bf16x8 a, bf16x8 b, f32x4 c){
  return __builtin_amdgcn_mfma_f32_16x16x32_bf16(a, b, c, 0, 0, 0);
}
__device__ __forceinline__ f32x2 bfcvt2(unsigned q){
  f32x2 r;
  r[0] = __builtin_bit_cast(float, q << 16);
  r[1] = __builtin_bit_cast(float, q & 0xffff0000u);
  return r;
}

// h-channel permutation: channel c lives at slot c' = (c&15)*16 + (c>>4).
// orig(c') = ((c'&15)<<4) | (c'>>4).

// ============ k0: weights fp32 -> bf16 MFMA fragment layout (+ tap repack) ============
__global__ __launch_bounds__(64) void k0_wfrag(
  const float* __restrict__ Wk, const float* __restrict__ Wq,
  const float* __restrict__ Wv, const float* __restrict__ Wr,
  const float* __restrict__ W1, const float* __restrict__ W2,
  const float* __restrict__ dww, const float* __restrict__ dwb,
  float* __restrict__ dwp, unsigned short* __restrict__ wf)
{
  const int bid = blockIdx.x, l = threadIdx.x;
  if (bid == 96){
    // taps+bias in k3 lane order: lane t owns slots c' = t*2, t*2+1.
    // dwp[t*20 + j*2 + jc] = tap j of orig(t*2+jc); dwp[t*20+18+jc] = bias.
    #pragma unroll
    for (int h=0; h<2; ++h){
      int tt = l + h*64;
      #pragma unroll
      for (int jc=0; jc<2; ++jc){
        int cp = tt*2 + jc;
        int f = ((cp&15)<<4) | (cp>>4);
        #pragma unroll
        for (int j=0;j<9;++j) dwp[tt*20 + j*2 + jc] = dww[f*9+j];
        dwp[tt*20 + 18 + jc] = dwb[f];
      }
    }
    return;
  }
  const float* src; int K, nt, ks; unsigned short* dst; bool perm = false;
  if (bid < 32){
    int w = bid>>3, f = bid&7;
    src = (w==0)?Wk:(w==1)?Wq:(w==2)?Wv:Wr;
    K = 64; nt = f>>1; ks = f&1;
    dst = wf + w*4096 + f*512;
  } else if (bid < 64){
    int f = bid-32; src = W1; K = 64; nt = f>>1; ks = f&1;
    dst = wf + 16384 + f*512;
  } else {
    int f = bid-64; src = W2; K = 256; nt = f>>3; ks = f&7;
    dst = wf + 32768 + f*512; perm = true;   // k index = permuted slot c'
  }
  u16x8 v;
  #pragma unroll
  for (int j=0;j<8;++j){
    int k = ks*32 + (l>>4)*8 + j;
    if (perm) k = ((k&15)<<4) | (k>>4);
    int n = nt*16 + (l&15);
    v[j] = f2bf(src[n*K + k]);
  }
  *reinterpret_cast<u16x8*>(dst + l*8) = v;
}

// ============ zhalo: zero g_h halo columns + shared zero-row ============
__global__ __launch_bounds__(256) void zhalo(unsigned* __restrict__ gh, unsigned* __restrict__ zr){
  int idx = blockIdx.x*256 + threadIdx.x;
  if (idx < 524288){
    int ch2 = idx & 127;
    int pos = idx >> 7;
    int side = pos & 1, row = pos >> 1;
    gh[(size_t)(row*HPITCH + side*(HPITCH-1))*128 + ch2] = 0;
  } else {
    int j = idx - 524288;
    if (j < HROW/2) zr[j] = 0;
  }
}

// ============ k1: LN1 + K/V proj (MFMA) + ctx accumulation (MFMA, LDS-transpose) ============
__global__ __launch_bounds__(256,2) void k1_ctx(
  const float* __restrict__ x, const float* __restrict__ g1, const float* __restrict__ be1,
  const float* __restrict__ bk, const float* __restrict__ bv,
  const unsigned short* __restrict__ wf,
  float* __restrict__ g_part, float* __restrict__ g_sump)
{
  __shared__ unsigned short tiles[4][4096];
  __shared__ float ctx_l[64*68];
  __shared__ float ssum_l[4][64];
  const int t = threadIdx.x, wid = t>>6, l = t&63;
  const int lg = l>>4, l15 = l&15;
  unsigned short* tile = tiles[wid];
  const int tok0 = blockIdx.x*512 + wid*128;

  bf16x8 WkF[8], WvF[8];
  #pragma unroll
  for (int f=0; f<8; ++f){
    WkF[f] = ldfrag_g(wf +    0 + f*512 + l*8);
    WvF[f] = ldfrag_g(wf + 8192 + f*512 + l*8);
  }
  float4 g1v  = *reinterpret_cast<const float4*>(&g1[l15*4]);
  float4 be1v = *reinterpret_cast<const float4*>(&be1[l15*4]);
  float bkv[4], bvv[4];
  #pragma unroll
  for (int ct=0; ct<4; ++ct){ bkv[ct]=bk[ct*16+l15]; bvv[ct]=bv[ct*16+l15]; }

  f32x4 acc[4][4];
  #pragma unroll
  for (int a=0;a<4;++a)
    #pragma unroll
    for (int b=0;b<4;++b) acc[a][b] = (f32x4){0.f,0.f,0.f,0.f};
  float sume[4] = {0.f,0.f,0.f,0.f};

  for (int tb=0; tb<2; ++tb){
    const int tbase = tok0 + tb*64;
    #pragma unroll
    for (int it=0; it<16; ++it){
      int row = it*4 + lg;
      float4 xv = *reinterpret_cast<const float4*>(&x[(size_t)(tbase+row)*64 + l15*4]);
      float s1 = xv.x+xv.y+xv.z+xv.w;
      float s2 = xv.x*xv.x + xv.y*xv.y + xv.z*xv.z + xv.w*xv.w;
      #pragma unroll
      for (int off=1; off<16; off<<=1){ s1 += __shfl_xor(s1,off,64); s2 += __shfl_xor(s2,off,64); }
      float mu = s1*(1.f/64.f);
      float rs = rsqrtf(s2*(1.f/64.f) - mu*mu + 1e-5f);
      uint2 pk = { pack2((xv.x-mu)*rs*g1v.x + be1v.x, (xv.y-mu)*rs*g1v.y + be1v.y),
                   pack2((xv.z-mu)*rs*g1v.z + be1v.z, (xv.w-mu)*rs*g1v.w + be1v.w) };
      *reinterpret_cast<uint2*>(&tile[row*64 + ((l15*4) ^ ((row&7)<<3))]) = pk;
    }
    bf16x8 aF[4][2];
    #pragma unroll
    for (int mt=0;mt<4;++mt){
      int row = mt*16+l15, sw=(row&7)<<3, ab=row*64;
      aF[mt][0] = __builtin_bit_cast(bf16x8, *reinterpret_cast<const u16x8*>(tile+ab+((     lg*8)^sw)));
      aF[mt][1] = __builtin_bit_cast(bf16x8, *reinterpret_cast<const u16x8*>(tile+ab+((32 + lg*8)^sw)));
    }
    #pragma unroll
    for (int half=0; half<2; ++half){
      #pragma unroll
      for (int m2=0;m2<2;++m2){
        const int mt = half*2+m2;
        #pragma unroll
        for (int ct=0;ct<4;++ct){
          f32x4 z = {0.f,0.f,0.f,0.f};
          z = mfma16(aF[mt][0], WkF[ct*2+0], z);
          z = mfma16(aF[mt][1], WkF[ct*2+1], z);
          float e0=__expf(z[0]+bkv[ct]), e1=__expf(z[1]+bkv[ct]);
          float e2=__expf(z[2]+bkv[ct]), e3=__expf(z[3]+bkv[ct]);
          sume[ct] += (e0+e1)+(e2+e3);
          const int c = ct*16+l15, sw = (c&7)<<3;
          const int cb = m2*16+lg*4;
          uint2 pe = { pack2(e0,e1), pack2(e2,e3) };
          *reinterpret_cast<uint2*>(&tile[c*64 + (cb ^ sw)]) = pe;
          f32x4 w = {0.f,0.f,0.f,0.f};
          w = mfma16(aF[mt][0], WvF[ct*2+0], w);
          w = mfma16(aF[mt][1], WvF[ct*2+1], w);
          uint2 pv = { pack2(w[0]+bvv[ct], w[1]+bvv[ct]), pack2(w[2]+bvv[ct], w[3]+bvv[ct]) };
          *reinterpret_cast<uint2*>(&tile[c*64 + ((32+cb) ^ sw)]) = pv;
        }
      }
      bf16x8 eA[4], vB[4];
      #pragma unroll
      for (int cm=0;cm<4;++cm){
        int row = cm*16+l15, sw=(row&7)<<3;
        eA[cm] = __builtin_bit_cast(bf16x8, *reinterpret_cast<const u16x8*>(tile + row*64 + ((     lg*8)^sw)));
        vB[cm] = __builtin_bit_cast(bf16x8, *reinterpret_cast<const u16x8*>(tile + row*64 + ((32 + lg*8)^sw)));
      }
      #pragma unroll
      for (int cm=0; cm<4; ++cm)
        #pragma unroll
        for (int jn=0; jn<4; ++jn)
          acc[cm][jn] = mfma16(eA[cm], vB[jn], acc[cm][jn]);
    }
  }
  #pragma unroll
  for (int ct=0; ct<4; ++ct){
    float s = sume[ct];
    s += __shfl_xor(s,16,64); s += __shfl_xor(s,32,64);
    if (lg==0) ssum_l[wid][ct*16+l15] = s;
  }
  #define CTX_RED(OP) \
    _Pragma("unroll") for (int cm=0;cm<4;++cm) \
    _Pragma("unroll") for (int jn=0;jn<4;++jn) \
    _Pragma("unroll") for (int r=0;r<4;++r) \
      ctx_l[(cm*16+lg*4+r)*68 + jn*16+l15] OP acc[cm][jn][r];
  if (wid==0){ CTX_RED(=) }  __syncthreads();
  if (wid==1){ CTX_RED(+=) } __syncthreads();
  if (wid==2){ CTX_RED(+=) } __syncthreads();
  if (wid==3){ CTX_RED(+=) } __syncthreads();
  #undef CTX_RED
  for (int i=t; i<4096; i+=256)
    g_part[(size_t)blockIdx.x*4096 + i] = ctx_l[(i>>6)*68 + (i&63)];
  if (t<64)
    g_sump[blockIdx.x*64 + t] = ssum_l[0][t]+ssum_l[1][t]+ssum_l[2][t]+ssum_l[3][t];
}

// ============ k15: reduce partials; ctxWr = (ctx_norm @ Wr^T) -> bf16 frags ============
__global__ __launch_bounds__(512) void k15_ctxwr(
  const float* __restrict__ g_part, const float* __restrict__ g_sump,
  const float* __restrict__ Wr, unsigned short* __restrict__ ctxWrF)
{
  __shared__ float sctx[4096];
  __shared__ float sWr[4096];
  __shared__ float sinv[64];
  const int b = blockIdx.x, t = threadIdx.x;
  if (t<64){
    float s=0.f;
    #pragma unroll 8
    for (int p=0;p<32;++p) s += g_sump[(b*32+p)*64 + t];
    sinv[t] = 1.f/s;
  }
  for (int idx=t; idx<4096; idx+=512){
    float s=0.f;
    #pragma unroll 8
    for (int p=0;p<32;++p) s += g_part[(size_t)(b*32+p)*4096 + idx];
    sctx[idx] = s;
  }
  __syncthreads();
  {
    int c = t>>3, d0 = (t&7)*8;
    float invc = sinv[c];
    #pragma unroll
    for (int dd=0; dd<8; ++dd){
      int d = d0+dd; float s = 0.f;
      #pragma unroll
      for (int v=0; v<64; ++v) s += sctx[c*64+v]*Wr[d*64+v];
      sWr[c*64+d] = s*invc;
    }
  }
  __syncthreads();
  {
    int f = t>>6, l = t&63, nt = f>>1, ks = f&1;
    u16x8 v;
    #pragma unroll
    for (int j=0;j<8;++j){
      int k = ks*32 + (l>>4)*8 + j;
      int n = nt*16 + (l&15);
      v[j] = f2bf(sWr[k*64+n]);
    }
    *reinterpret_cast<u16x8*>(ctxWrF + b*4096 + f*512 + l*8) = v;
  }
}

// ============ k2: LN1 + q-softmax + attn + residual + LN2 + W1 (mt-outer, wide stores) ============
__global__ __launch_bounds__(256,2) void k2_attn_ffn1(
  const float* __restrict__ x,
  const float* __restrict__ g1, const float* __restrict__ be1,
  const float* __restrict__ bq, const float* __restrict__ br,
  const float* __restrict__ g2, const float* __restrict__ be2,
  const float* __restrict__ b1,
  const unsigned short* __restrict__ wf,
  const unsigned short* __restrict__ ctxWrF,
  unsigned short* __restrict__ g_txb, unsigned short* __restrict__ g_h)
{
  __shared__ unsigned short tiles[4][4096];
  const int t = threadIdx.x, wid = t>>6, l = t&63;
  const int l15 = l&15, lg = l>>4;
  unsigned short* tile = tiles[wid];
  const int tok0 = (blockIdx.x*4 + wid)*64;
  const int img  = blockIdx.x>>6;
  const int yrow = (tok0>>7)&127;
  const int xb   = tok0&127;
  const size_t hbase = ((size_t)(img*128 + yrow)*HPITCH + 1 + xb)*256;

  bf16x8 WqF[8], CWF[8];
  #pragma unroll
  for (int f=0; f<8; ++f){
    WqF[f] = ldfrag_g(wf + 4096 + f*512 + l*8);
    CWF[f] = ldfrag_g(ctxWrF + img*4096 + f*512 + l*8);
  }
  float4 g1v  = *reinterpret_cast<const float4*>(&g1[l15*4]);
  float4 be1v = *reinterpret_cast<const float4*>(&be1[l15*4]);
  float bqv[4], brv[4], g2v[4], be2v[4];
  #pragma unroll
  for (int nt=0; nt<4; ++nt){
    bqv[nt]=bq[nt*16+l15]; brv[nt]=br[nt*16+l15];
    g2v[nt]=g2[nt*16+l15]; be2v[nt]=be2[nt*16+l15];
  }
  float b1v[16];
  #pragma unroll
  for (int i=0;i<16;++i) b1v[i]=b1[i*16+l15];

  // ---- LN1 -> swizzled bf16 tile ----
  #pragma unroll
  for (int it=0; it<16; ++it){
    int row = it*4 + lg;
    float4 xv = *reinterpret_cast<const float4*>(&x[(size_t)(tok0+row)*64 + l15*4]);
    float s1 = xv.x+xv.y+xv.z+xv.w;
    float s2 = xv.x*xv.x + xv.y*xv.y + xv.z*xv.z + xv.w*xv.w;
    #pragma unroll
    for (int off=1; off<16; off<<=1){ s1 += __shfl_xor(s1,off,64); s2 += __shfl_xor(s2,off,64); }
    float mu = s1*(1.f/64.f);
    float rs = rsqrtf(s2*(1.f/64.f) - mu*mu + 1e-5f);
    uint2 pk = { pack2((xv.x-mu)*rs*g1v.x + be1v.x, (xv.y-mu)*rs*g1v.y + be1v.y),
                 pack2((xv.z-mu)*rs*g1v.z + be1v.z, (xv.w-mu)*rs*g1v.w + be1v.w) };
    *reinterpret_cast<uint2*>(&tile[row*64 + ((l15*4) ^ ((row&7)<<3))]) = pk;
  }

  // ---- phase A: per m-tile attn chain; leaves n2 in the tile ----
  for (int mt=0; mt<4; ++mt){
    const int arow = mt*16 + l15;
    const int asw  = (arow&7)<<3;
    const int abase= arow*64;
    bf16x8 a0 = __builtin_bit_cast(bf16x8, *reinterpret_cast<const u16x8*>(tile + abase + ((     lg*8) ^ asw)));
    bf16x8 a1 = __builtin_bit_cast(bf16x8, *reinterpret_cast<const u16x8*>(tile + abase + ((32 + lg*8) ^ asw)));
    f32x4 qa[4];
    #pragma unroll
    for (int nt=0; nt<4; ++nt){
      f32x4 z = {0.f,0.f,0.f,0.f};
      z = mfma16(a0, WqF[nt*2+0], z);
      z = mfma16(a1, WqF[nt*2+1], z);
      qa[nt] = z;
    }
    #pragma unroll
    for (int nt=0; nt<4; ++nt)
      #pragma unroll
      for (int r=0; r<4; ++r) qa[nt][r] += bqv[nt];
    float mx[4];
    #pragma unroll
    for (int r=0;r<4;++r) mx[r] = fmaxf(fmaxf(qa[0][r],qa[1][r]), fmaxf(qa[2][r],qa[3][r]));
    #pragma unroll
    for (int off=1; off<16; off<<=1)
      #pragma unroll
      for (int r=0;r<4;++r) mx[r] = fmaxf(mx[r], __shfl_xor(mx[r], off, 64));
    float sm[4] = {0.f,0.f,0.f,0.f};
    #pragma unroll
    for (int nt=0;nt<4;++nt)
      #pragma unroll
      for (int r=0;r<4;++r){ float e = __expf(qa[nt][r]-mx[r]); qa[nt][r]=e; sm[r]+=e; }
    #pragma unroll
    for (int off=1; off<16; off<<=1)
      #pragma unroll
      for (int r=0;r<4;++r) sm[r] += __shfl_xor(sm[r], off, 64);
    float inv[4];
    #pragma unroll
    for (int r=0;r<4;++r) inv[r] = 1.f/sm[r];
    #pragma unroll
    for (int nt=0;nt<4;++nt)
      #pragma unroll
      for (int r=0;r<4;++r){
        int row = mt*16 + lg*4 + r, col = nt*16 + l15;
        tile[row*64 + (col ^ ((row&7)<<3))] = f2bf(qa[nt][r]*inv[r]);
      }
    bf16x8 p0 = __builtin_bit_cast(bf16x8, *reinterpret_cast<const u16x8*>(tile + abase + ((     lg*8) ^ asw)));
    bf16x8 p1 = __builtin_bit_cast(bf16x8, *reinterpret_cast<const u16x8*>(tile + abase + ((32 + lg*8) ^ asw)));
    f32x4 ao[4];
    #pragma unroll
    for (int nt=0; nt<4; ++nt){
      f32x4 z = {0.f,0.f,0.f,0.f};
      z = mfma16(p0, CWF[nt*2+0], z);
      z = mfma16(p1, CWF[nt*2+1], z);
      ao[nt] = z;
    }
    float txv[4][4];
    float s1v[4] = {0.f,0.f,0.f,0.f}, s2v[4] = {0.f,0.f,0.f,0.f};
    #pragma unroll
    for (int nt=0;nt<4;++nt)
      #pragma unroll
      for (int r=0;r<4;++r){
        size_t row = (size_t)(tok0 + mt*16 + lg*4 + r);
        float v = ao[nt][r] + brv[nt] + x[row*64 + nt*16+l15];
        g_txb[row*64 + nt*16+l15] = f2bf(v);
        txv[nt][r] = v; s1v[r] += v; s2v[r] += v*v;
      }
    #pragma unroll
    for (int off=1; off<16; off<<=1)
      #pragma unroll
      for (int r=0;r<4;++r){ s1v[r] += __shfl_xor(s1v[r], off, 64); s2v[r] += __shfl_xor(s2v[r], off, 64); }
    #pragma unroll
    for (int r=0;r<4;++r){
      float mu2 = s1v[r]*(1.f/64.f);
      float rs  = rsqrtf(s2v[r]*(1.f/64.f) - mu2*mu2 + 1e-5f);
      s1v[r] = mu2; s2v[r] = rs;
    }
    #pragma unroll
    for (int nt=0;nt<4;++nt)
      #pragma unroll
      for (int r=0;r<4;++r){
        int row = mt*16 + lg*4 + r, col = nt*16 + l15;
        float n2 = (txv[nt][r]-s1v[r])*s2v[r]*g2v[nt] + be2v[nt];
        tile[row*64 + (col ^ ((row&7)<<3))] = f2bf(n2);
      }
  }

  // ---- phase B: h = n2 @ W1^T + b1; mt-outer, register-stash, wide PERMUTED stores ----
  // channel c = nt2*16 + l15 stored at slot c' = l15*16 + nt2  => lane-contiguous rows.
  for (int mt=0; mt<4; ++mt){
    const int arow = mt*16 + l15;
    const int asw  = (arow&7)<<3;
    const int abase= arow*64;
    bf16x8 n20 = __builtin_bit_cast(bf16x8, *reinterpret_cast<const u16x8*>(tile + abase + ((     lg*8) ^ asw)));
    bf16x8 n21 = __builtin_bit_cast(bf16x8, *reinterpret_cast<const u16x8*>(tile + abase + ((32 + lg*8) ^ asw)));
    unsigned hpk[4][8];
    #pragma unroll
    for (int np=0; np<8; ++np){
      bf16x8 wa0 = ldfrag_g(wf + 16384 + (np*4+0)*512 + l*8);
      bf16x8 wa1 = ldfrag_g(wf + 16384 + (np*4+1)*512 + l*8);
      bf16x8 wb0 = ldfrag_g(wf + 16384 + (np*4+2)*512 + l*8);
      bf16x8 wb1 = ldfrag_g(wf + 16384 + (np*4+3)*512 + l*8);
      float ba = b1v[np*2], bb = b1v[np*2+1];
      f32x4 ha = {ba,ba,ba,ba};
      ha = mfma16(n20, wa0, ha);
      ha = mfma16(n21, wa1, ha);
      f32x4 hb = {bb,bb,bb,bb};
      hb = mfma16(n20, wb0, hb);
      hb = mfma16(n21, wb1, hb);
      #pragma unroll
      for (int r=0;r<4;++r) hpk[r][np] = pack2(ha[r], hb[r]);
    }
    #pragma unroll
    for (int r=0;r<4;++r){
      const size_t ro = hbase + (size_t)(mt*16+lg*4+r)*256 + l15*16;
      uint4 v0 = { hpk[r][0], hpk[r][1], hpk[r][2], hpk[r][3] };
      uint4 v1 = { hpk[r][4], hpk[r][5], hpk[r][6], hpk[r][7] };
      *reinterpret_cast<uint4*>(&g_h[ro])   = v0;
      *reinterpret_cast<uint4*>(&g_h[ro+8]) = v1;
    }
  }
}

// ============ k3: depthwise conv3x3 + GELU + W2 ============
// 128-thread blocks (2 waves), one 16-token strip per block. Each lane owns 2
// permuted channels for the conv; waves split 256 channels. One barrier; each
// wave then computes 2 output quarters of the W2 GEMM over full K=256.
__global__ __launch_bounds__(128,6) void k3_conv_ffn2(
  const unsigned short* __restrict__ g_h,
  const unsigned short* __restrict__ zrow,
  const float* __restrict__ dwp,
  const float* __restrict__ b2,
  const unsigned short* __restrict__ wf,
  const unsigned short* __restrict__ g_txb, float* __restrict__ out)
{
  __shared__ unsigned short tile[4096];   // [16 tok][256 ch'] swizzled, 8 KB
  const int t = threadIdx.x, wv = t>>6, l = t&63;
  const int l15 = l&15, lg = l>>4;
  const int blk = (blockIdx.x & 7)*2048 + (blockIdx.x >> 3);   // XCD-chunked remap
  const int tok0 = blk*16;
  const int img  = tok0>>14;
  const int y    = (tok0>>7)&127;
  const int x0   = tok0&127;
  const bool okm = (y>0), okp = (y<127);

  // taps + bias for this lane's 2 channels (k0 pre-permuted)
  f32x2 cw[9];
  #pragma unroll
  for (int j=0;j<9;++j)
    cw[j] = *reinterpret_cast<const f32x2*>(&dwp[t*20 + j*2]);
  f32x2 cb2 = *reinterpret_cast<const f32x2*>(&dwp[t*20 + 18]);

  const size_t base = ((size_t)(img*128+y)*HPITCH + x0)*256;
  const unsigned short* rB = g_h + base + t*2;
  const unsigned short* rA = okm ? (rB - HROW) : (zrow + t*2);
  const unsigned short* rC = okp ? (rB + HROW) : (zrow + t*2);

  auto ldr = [](const unsigned short* pp, int o) -> unsigned {
    return *reinterpret_cast<const unsigned*>(pp + o*256);
  };

  // gelu constants with log2(e) folded: g = a / (1 + exp2(a*(C0 + C1*a^2)))
  const f32x2 kC0 = {-2.3022082f,-2.3022082f};
  const f32x2 kC1 = {-0.1029432f,-0.1029432f};

  // pipeline: positions 0,1 converted; 2,3,4 raw in flight
  f32x2 PA=bfcvt2(ldr(rA,0)), PB=bfcvt2(ldr(rB,0)), PC=bfcvt2(ldr(rC,0));
  f32x2 CA=bfcvt2(ldr(rA,1)), CB=bfcvt2(ldr(rB,1)), CC=bfcvt2(ldr(rC,1));
  unsigned r2A=ldr(rA,2), r2B=ldr(rB,2), r2C=ldr(rC,2);
  unsigned r3A=ldr(rA,3), r3B=ldr(rB,3), r3C=ldr(rC,3);
  unsigned r4A=ldr(rA,4), r4B=ldr(rB,4), r4C=ldr(rC,4);

  #pragma unroll 4
  for (int s=0; s<16; ++s){
    const int o = (s<13) ? (s+5) : 17;
    unsigned r5A=ldr(rA,o), r5B=ldr(rB,o), r5C=ldr(rC,o);
    f32x2 NA=bfcvt2(r2A), NB=bfcvt2(r2B), NC=bfcvt2(r2C);
    f32x2 a = cb2;
    a += cw[0]*PA; a += cw[1]*CA; a += cw[2]*NA;
    a += cw[3]*PB; a += cw[4]*CB; a += cw[5]*NB;
    a += cw[6]*PC; a += cw[7]*CC; a += cw[8]*NC;
    f32x2 u = a*a;
    f32x2 w = u*kC1 + kC0;
    f32x2 arg = a*w;
    f32x2 e;
    e[0]=__builtin_amdgcn_exp2f(arg[0]); e[1]=__builtin_amdgcn_exp2f(arg[1]);
    f32x2 den = e + (f32x2){1.f,1.f};
    f32x2 rc;
    rc[0]=__builtin_amdgcn_rcpf(den[0]); rc[1]=__builtin_amdgcn_rcpf(den[1]);
    f32x2 g = a*rc;
    unsigned pk;
    asm("v_cvt_pk_bf16_f32 %0, %1, %2" : "=v"(pk) : "v"(g[0]), "v"(g[1]));
    *reinterpret_cast<unsigned*>(&tile[s*256 + ((t*2) ^ ((s&7)<<3))]) = pk;
    PA=CA; PB=CB; PC=CC; CA=NA; CB=NB; CC=NC;
    r2A=r3A; r2B=r3B; r2C=r3C;
    r3A=r4A; r3B=r4B; r3C=r4C;
    r4A=r5A; r4B=r5B; r4C=r5C;
  }

  __syncthreads();

  // W2 GEMM: wave wv -> output quarters ntc = wv*2, wv*2+1; K=256 over 4 i-tiles
  f32x4 oacc0 = {0.f,0.f,0.f,0.f};
  f32x4 oacc1 = {0.f,0.f,0.f,0.f};
  const int ntcA = wv*2, ntcB = wv*2+1;
  #pragma unroll
  for (int i=0;i<4;++i){
    const int n = l15;
    const int nsw = (n&7)<<3;
    const int cb0 = (i*64      + lg*8) ^ nsw;
    const int cb1 = (i*64 + 32 + lg*8) ^ nsw;
    bf16x8 fb0 = __builtin_bit_cast(bf16x8, *reinterpret_cast<const u16x8*>(&tile[n*256 + cb0]));
    bf16x8 fb1 = __builtin_bit_cast(bf16x8, *reinterpret_cast<const u16x8*>(&tile[n*256 + cb1]));
    bf16x8 WA0 = ldfrag_g(wf + 32768 + (ntcA*8 + i*2+0)*512 + l*8);
    bf16x8 WA1 = ldfrag_g(wf + 32768 + (ntcA*8 + i*2+1)*512 + l*8);
    bf16x8 WB0 = ldfrag_g(wf + 32768 + (ntcB*8 + i*2+0)*512 + l*8);
    bf16x8 WB1 = ldfrag_g(wf + 32768 + (ntcB*8 + i*2+1)*512 + l*8);
    oacc0 = mfma16(WA0, fb0, oacc0);
    oacc0 = mfma16(WA1, fb1, oacc0);
    oacc1 = mfma16(WB0, fb0, oacc1);
    oacc1 = mfma16(WB1, fb1, oacc1);
  }

  // ---- vector epilogue ----
  #pragma unroll
  for (int q=0;q<2;++q){
    const int ntc = wv*2+q;
    const size_t off = (size_t)(tok0 + l15)*64 + ntc*16 + lg*4;
    u16x4v tq = *reinterpret_cast<const u16x4v*>(&g_txb[off]);
    float4 b2q = *reinterpret_cast<const float4*>(&b2[ntc*16 + lg*4]);
    f32x4 oc = q ? oacc1 : oacc0;
    float4 o;
    o.x = oc[0] + b2q.x + bf2f(tq[0]);
    o.y = oc[1] + b2q.y + bf2f(tq[1]);
    o.z = oc[2] + b2q.z + bf2f(tq[2]);
    o.w = oc[3] + b2q.w + bf2f(tq[3]);
    *reinterpret_cast<float4*>(&out[off]) = o;
  }
}

extern "C" void kernel_launch(void* const* d_in, const int* in_sizes, int n_in,
                              void* d_out, int out_size, void* d_ws, size_t ws_size,
                              hipStream_t stream)
{
  const float* x  =(const float*)d_in[0];
  const float* g1 =(const float*)d_in[3];
  const float* be1=(const float*)d_in[4];
  const float* Wk =(const float*)d_in[5];
  const float* bk =(const float*)d_in[6];
  const float* Wq =(const float*)d_in[7];
  const float* bq =(const float*)d_in[8];
  const float* Wv =(const float*)d_in[9];
  const float* bv =(const float*)d_in[10];
  const float* Wr =(const float*)d_in[11];
  const float* br =(const float*)d_in[12];
  const float* g2 =(const float*)d_in[13];
  const float* be2=(const float*)d_in[14];
  const float* W1 =(const float*)d_in[15];
  const float* b1 =(const float*)d_in[16];
  const float* dww=(const float*)d_in[17];
  const float* dwb=(const float*)d_in[18];
  const float* W2 =(const float*)d_in[19];
  const float* b2 =(const float*)d_in[20];
  float* outp = (float*)d_out;
  char* ws = (char*)d_ws;

  unsigned short* wfb    = (unsigned short*)ws;                 // 96KB
  unsigned short* ctxWrF = (unsigned short*)(ws + 98304);       // 128KB
  float* g_sump = (float*)(ws + 229376);                        // 128KB
  float* g_part = (float*)(ws + 393216);                        // 8MB
  unsigned short* g_txb = (unsigned short*)(ws + 16777216);     // 32MB bf16
  unsigned short* g_h   = (unsigned short*)(ws + 50331648);     // 136.3MB padded bf16
  unsigned short* zr    = (unsigned short*)(ws + 186646528);    // 65KB zero row
  float* dwp            = (float*)(ws + 186712064);             // 10.25KB repacked taps+bias

  hipLaunchKernelGGL(k0_wfrag, dim3(97), dim3(64), 0, stream, Wk, Wq, Wv, Wr, W1, W2, dww, dwb, dwp, wfb);
  hipLaunchKernelGGL(zhalo, dim3(2113), dim3(256), 0, stream, (unsigned*)g_h, (unsigned*)zr);
  hipLaunchKernelGGL(k1_ctx, dim3(512), dim3(256), 0, stream, x, g1, be1, bk, bv, wfb, g_part, g_sump);
  hipLaunchKernelGGL(k15_ctxwr, dim3(16), dim3(512), 0, stream, g_part, g_sump, Wr, ctxWrF);
  hipLaunchKernelGGL(k2_attn_ffn1, dim3(1024), dim3(256), 0, stream,
                     x, g1, be1, bq, br, g2, be2, b1, wfb, ctxWrF, g_txb, g_h);
  hipLaunchKernelGGL(k3_conv_ffn2, dim3(16384), dim3(128), 0, stream,
                     g_h, zr, dwp, b2, wfb, g_txb, outp);
}

// Round 5
// 236.850 us; speedup vs baseline: 1.1154x; 1.0473x over previous
//
#include <hip/hip_runtime.h>
#include <math.h>

typedef __bf16 bf16x8 __attribute__((ext_vector_type(8)));
typedef float f32x4 __attribute__((ext_vector_type(4)));
typedef float f32x2 __attribute__((ext_vector_type(2)));
typedef unsigned short u16x8 __attribute__((ext_vector_type(8)));
typedef unsigned short u16x4v __attribute__((ext_vector_type(4)));

constexpr int NIMG = 16384;   // H*W
constexpr int HPITCH = 130;   // padded row pitch (tokens) for g_h
constexpr int HROW = HPITCH*256; // shorts per padded image row

__device__ __forceinline__ unsigned short f2bf(float f){
  unsigned u = __builtin_bit_cast(unsigned, f);
  u += 0x7fffu + ((u>>16)&1u);
  return (unsigned short)(u>>16);
}
__device__ __forceinline__ unsigned pack2(float a, float b){
  return (unsigned)f2bf(a) | ((unsigned)f2bf(b)<<16);
}
__device__ __forceinline__ float bf2f(unsigned short h){
  unsigned u = ((unsigned)h)<<16;
  return __builtin_bit_cast(float, u);
}
__device__ __forceinline__ bf16x8 ldfrag_g(const unsigned short* p){
  u16x8 v = *reinterpret_cast<const u16x8*>(p);
  return __builtin_bit_cast(bf16x8, v);
}
__device__ __forceinline__ f32x4 mfma16(bf16x8 a, bf16x8 b, f32x4 c){
  return __builtin_amdgcn_mfma_f32_16x16x32_bf16(a, b, c, 0, 0, 0);
}

// h-channel permutation: channel c lives at slot c' = (c&15)*16 + (c>>4).
// orig(c') = ((c'&15)<<4) | (c'>>4).

// ============ k0: weights fp32 -> bf16 MFMA fragment layout (+ tap repack) ============
__global__ __launch_bounds__(64) void k0_wfrag(
  const float* __restrict__ Wk, const float* __restrict__ Wq,
  const float* __restrict__ Wv, const float* __restrict__ Wr,
  const float* __restrict__ W1, const float* __restrict__ W2,
  const float* __restrict__ dww, const float* __restrict__ dwb,
  float* __restrict__ dwp, unsigned short* __restrict__ wf)
{
  const int bid = blockIdx.x, l = threadIdx.x;
  if (bid == 96){
    // taps+bias keyed by permuted slot c': dwp[c'*12 + j] (j=0..8 taps, 9=bias)
    #pragma unroll
    for (int c=0;c<4;++c){
      int cp = l*4 + c;
      int f = ((cp&15)<<4) | (cp>>4);
      #pragma unroll
      for (int j=0;j<9;++j) dwp[cp*12 + j] = dww[f*9+j];
      dwp[cp*12 + 9]  = dwb[f];
      dwp[cp*12 + 10] = 0.f;
      dwp[cp*12 + 11] = 0.f;
    }
    return;
  }
  const float* src; int K, nt, ks; unsigned short* dst; bool perm = false;
  if (bid < 32){
    int w = bid>>3, f = bid&7;
    src = (w==0)?Wk:(w==1)?Wq:(w==2)?Wv:Wr;
    K = 64; nt = f>>1; ks = f&1;
    dst = wf + w*4096 + f*512;
  } else if (bid < 64){
    int f = bid-32; src = W1; K = 64; nt = f>>1; ks = f&1;
    dst = wf + 16384 + f*512;
  } else {
    int f = bid-64; src = W2; K = 256; nt = f>>3; ks = f&7;
    dst = wf + 32768 + f*512; perm = true;   // k index = permuted slot c'
  }
  u16x8 v;
  #pragma unroll
  for (int j=0;j<8;++j){
    int k = ks*32 + (l>>4)*8 + j;
    if (perm) k = ((k&15)<<4) | (k>>4);
    int n = nt*16 + (l&15);
    v[j] = f2bf(src[n*K + k]);
  }
  *reinterpret_cast<u16x8*>(dst + l*8) = v;
}

// ============ zhalo: zero g_h halo columns + shared zero-row ============
__global__ __launch_bounds__(256) void zhalo(unsigned* __restrict__ gh, unsigned* __restrict__ zr){
  int idx = blockIdx.x*256 + threadIdx.x;
  if (idx < 524288){
    int ch2 = idx & 127;
    int pos = idx >> 7;
    int side = pos & 1, row = pos >> 1;
    gh[(size_t)(row*HPITCH + side*(HPITCH-1))*128 + ch2] = 0;
  } else {
    int j = idx - 524288;
    if (j < HROW/2) zr[j] = 0;
  }
}

// ============ k1: LN1 + K/V proj (MFMA) + ctx accumulation (MFMA, LDS-transpose) ============
__global__ __launch_bounds__(256,2) void k1_ctx(
  const float* __restrict__ x, const float* __restrict__ g1, const float* __restrict__ be1,
  const float* __restrict__ bk, const float* __restrict__ bv,
  const unsigned short* __restrict__ wf,
  float* __restrict__ g_part, float* __restrict__ g_sump)
{
  __shared__ unsigned short tiles[4][4096];
  __shared__ float ctx_l[64*68];
  __shared__ float ssum_l[4][64];
  const int t = threadIdx.x, wid = t>>6, l = t&63;
  const int lg = l>>4, l15 = l&15;
  unsigned short* tile = tiles[wid];
  const int tok0 = blockIdx.x*512 + wid*128;

  bf16x8 WkF[8], WvF[8];
  #pragma unroll
  for (int f=0; f<8; ++f){
    WkF[f] = ldfrag_g(wf +    0 + f*512 + l*8);
    WvF[f] = ldfrag_g(wf + 8192 + f*512 + l*8);
  }
  float4 g1v  = *reinterpret_cast<const float4*>(&g1[l15*4]);
  float4 be1v = *reinterpret_cast<const float4*>(&be1[l15*4]);
  float bkv[4], bvv[4];
  #pragma unroll
  for (int ct=0; ct<4; ++ct){ bkv[ct]=bk[ct*16+l15]; bvv[ct]=bv[ct*16+l15]; }

  f32x4 acc[4][4];
  #pragma unroll
  for (int a=0;a<4;++a)
    #pragma unroll
    for (int b=0;b<4;++b) acc[a][b] = (f32x4){0.f,0.f,0.f,0.f};
  float sume[4] = {0.f,0.f,0.f,0.f};

  for (int tb=0; tb<2; ++tb){
    const int tbase = tok0 + tb*64;
    #pragma unroll
    for (int it=0; it<16; ++it){
      int row = it*4 + lg;
      float4 xv = *reinterpret_cast<const float4*>(&x[(size_t)(tbase+row)*64 + l15*4]);
      float s1 = xv.x+xv.y+xv.z+xv.w;
      float s2 = xv.x*xv.x + xv.y*xv.y + xv.z*xv.z + xv.w*xv.w;
      #pragma unroll
      for (int off=1; off<16; off<<=1){ s1 += __shfl_xor(s1,off,64); s2 += __shfl_xor(s2,off,64); }
      float mu = s1*(1.f/64.f);
      float rs = rsqrtf(s2*(1.f/64.f) - mu*mu + 1e-5f);
      uint2 pk = { pack2((xv.x-mu)*rs*g1v.x + be1v.x, (xv.y-mu)*rs*g1v.y + be1v.y),
                   pack2((xv.z-mu)*rs*g1v.z + be1v.z, (xv.w-mu)*rs*g1v.w + be1v.w) };
      *reinterpret_cast<uint2*>(&tile[row*64 + ((l15*4) ^ ((row&7)<<3))]) = pk;
    }
    bf16x8 aF[4][2];
    #pragma unroll
    for (int mt=0;mt<4;++mt){
      int row = mt*16+l15, sw=(row&7)<<3, ab=row*64;
      aF[mt][0] = __builtin_bit_cast(bf16x8, *reinterpret_cast<const u16x8*>(tile+ab+((     lg*8)^sw)));
      aF[mt][1] = __builtin_bit_cast(bf16x8, *reinterpret_cast<const u16x8*>(tile+ab+((32 + lg*8)^sw)));
    }
    #pragma unroll
    for (int half=0; half<2; ++half){
      #pragma unroll
      for (int m2=0;m2<2;++m2){
        const int mt = half*2+m2;
        #pragma unroll
        for (int ct=0;ct<4;++ct){
          f32x4 z = {0.f,0.f,0.f,0.f};
          z = mfma16(aF[mt][0], WkF[ct*2+0], z);
          z = mfma16(aF[mt][1], WkF[ct*2+1], z);
          float e0=__expf(z[0]+bkv[ct]), e1=__expf(z[1]+bkv[ct]);
          float e2=__expf(z[2]+bkv[ct]), e3=__expf(z[3]+bkv[ct]);
          sume[ct] += (e0+e1)+(e2+e3);
          const int c = ct*16+l15, sw = (c&7)<<3;
          const int cb = m2*16+lg*4;
          uint2 pe = { pack2(e0,e1), pack2(e2,e3) };
          *reinterpret_cast<uint2*>(&tile[c*64 + (cb ^ sw)]) = pe;
          f32x4 w = {0.f,0.f,0.f,0.f};
          w = mfma16(aF[mt][0], WvF[ct*2+0], w);
          w = mfma16(aF[mt][1], WvF[ct*2+1], w);
          uint2 pv = { pack2(w[0]+bvv[ct], w[1]+bvv[ct]), pack2(w[2]+bvv[ct], w[3]+bvv[ct]) };
          *reinterpret_cast<uint2*>(&tile[c*64 + ((32+cb) ^ sw)]) = pv;
        }
      }
      bf16x8 eA[4], vB[4];
      #pragma unroll
      for (int cm=0;cm<4;++cm){
        int row = cm*16+l15, sw=(row&7)<<3;
        eA[cm] = __builtin_bit_cast(bf16x8, *reinterpret_cast<const u16x8*>(tile + row*64 + ((     lg*8)^sw)));
        vB[cm] = __builtin_bit_cast(bf16x8, *reinterpret_cast<const u16x8*>(tile + row*64 + ((32 + lg*8)^sw)));
      }
      #pragma unroll
      for (int cm=0; cm<4; ++cm)
        #pragma unroll
        for (int jn=0; jn<4; ++jn)
          acc[cm][jn] = mfma16(eA[cm], vB[jn], acc[cm][jn]);
    }
  }
  #pragma unroll
  for (int ct=0; ct<4; ++ct){
    float s = sume[ct];
    s += __shfl_xor(s,16,64); s += __shfl_xor(s,32,64);
    if (lg==0) ssum_l[wid][ct*16+l15] = s;
  }
  #define CTX_RED(OP) \
    _Pragma("unroll") for (int cm=0;cm<4;++cm) \
    _Pragma("unroll") for (int jn=0;jn<4;++jn) \
    _Pragma("unroll") for (int r=0;r<4;++r) \
      ctx_l[(cm*16+lg*4+r)*68 + jn*16+l15] OP acc[cm][jn][r];
  if (wid==0){ CTX_RED(=) }  __syncthreads();
  if (wid==1){ CTX_RED(+=) } __syncthreads();
  if (wid==2){ CTX_RED(+=) } __syncthreads();
  if (wid==3){ CTX_RED(+=) } __syncthreads();
  #undef CTX_RED
  for (int i=t; i<4096; i+=256)
    g_part[(size_t)blockIdx.x*4096 + i] = ctx_l[(i>>6)*68 + (i&63)];
  if (t<64)
    g_sump[blockIdx.x*64 + t] = ssum_l[0][t]+ssum_l[1][t]+ssum_l[2][t]+ssum_l[3][t];
}

// ============ k15: reduce partials; ctxWr = (ctx_norm @ Wr^T) -> bf16 frags ============
__global__ __launch_bounds__(512) void k15_ctxwr(
  const float* __restrict__ g_part, const float* __restrict__ g_sump,
  const float* __restrict__ Wr, unsigned short* __restrict__ ctxWrF)
{
  __shared__ float sctx[4096];
  __shared__ float sWr[4096];
  __shared__ float sinv[64];
  const int b = blockIdx.x, t = threadIdx.x;
  if (t<64){
    float s=0.f;
    #pragma unroll 8
    for (int p=0;p<32;++p) s += g_sump[(b*32+p)*64 + t];
    sinv[t] = 1.f/s;
  }
  for (int idx=t; idx<4096; idx+=512){
    float s=0.f;
    #pragma unroll 8
    for (int p=0;p<32;++p) s += g_part[(size_t)(b*32+p)*4096 + idx];
    sctx[idx] = s;
  }
  __syncthreads();
  {
    int c = t>>3, d0 = (t&7)*8;
    float invc = sinv[c];
    #pragma unroll
    for (int dd=0; dd<8; ++dd){
      int d = d0+dd; float s = 0.f;
      #pragma unroll
      for (int v=0; v<64; ++v) s += sctx[c*64+v]*Wr[d*64+v];
      sWr[c*64+d] = s*invc;
    }
  }
  __syncthreads();
  {
    int f = t>>6, l = t&63, nt = f>>1, ks = f&1;
    u16x8 v;
    #pragma unroll
    for (int j=0;j<8;++j){
      int k = ks*32 + (l>>4)*8 + j;
      int n = nt*16 + (l&15);
      v[j] = f2bf(sWr[k*64+n]);
    }
    *reinterpret_cast<u16x8*>(ctxWrF + b*4096 + f*512 + l*8) = v;
  }
}

// ============ k2: LN1 + q-softmax + attn + residual + LN2 + W1 (mt-outer, wide stores) ============
__global__ __launch_bounds__(256,2) void k2_attn_ffn1(
  const float* __restrict__ x,
  const float* __restrict__ g1, const float* __restrict__ be1,
  const float* __restrict__ bq, const float* __restrict__ br,
  const float* __restrict__ g2, const float* __restrict__ be2,
  const float* __restrict__ b1,
  const unsigned short* __restrict__ wf,
  const unsigned short* __restrict__ ctxWrF,
  unsigned short* __restrict__ g_txb, unsigned short* __restrict__ g_h)
{
  __shared__ unsigned short tiles[4][4096];
  const int t = threadIdx.x, wid = t>>6, l = t&63;
  const int l15 = l&15, lg = l>>4;
  unsigned short* tile = tiles[wid];
  const int tok0 = (blockIdx.x*4 + wid)*64;
  const int img  = blockIdx.x>>6;
  const int yrow = (tok0>>7)&127;
  const int xb   = tok0&127;
  const size_t hbase = ((size_t)(img*128 + yrow)*HPITCH + 1 + xb)*256;

  bf16x8 WqF[8], CWF[8];
  #pragma unroll
  for (int f=0; f<8; ++f){
    WqF[f] = ldfrag_g(wf + 4096 + f*512 + l*8);
    CWF[f] = ldfrag_g(ctxWrF + img*4096 + f*512 + l*8);
  }
  float4 g1v  = *reinterpret_cast<const float4*>(&g1[l15*4]);
  float4 be1v = *reinterpret_cast<const float4*>(&be1[l15*4]);
  float bqv[4], brv[4], g2v[4], be2v[4];
  #pragma unroll
  for (int nt=0; nt<4; ++nt){
    bqv[nt]=bq[nt*16+l15]; brv[nt]=br[nt*16+l15];
    g2v[nt]=g2[nt*16+l15]; be2v[nt]=be2[nt*16+l15];
  }
  float b1v[16];
  #pragma unroll
  for (int i=0;i<16;++i) b1v[i]=b1[i*16+l15];

  // ---- LN1 -> swizzled bf16 tile ----
  #pragma unroll
  for (int it=0; it<16; ++it){
    int row = it*4 + lg;
    float4 xv = *reinterpret_cast<const float4*>(&x[(size_t)(tok0+row)*64 + l15*4]);
    float s1 = xv.x+xv.y+xv.z+xv.w;
    float s2 = xv.x*xv.x + xv.y*xv.y + xv.z*xv.z + xv.w*xv.w;
    #pragma unroll
    for (int off=1; off<16; off<<=1){ s1 += __shfl_xor(s1,off,64); s2 += __shfl_xor(s2,off,64); }
    float mu = s1*(1.f/64.f);
    float rs = rsqrtf(s2*(1.f/64.f) - mu*mu + 1e-5f);
    uint2 pk = { pack2((xv.x-mu)*rs*g1v.x + be1v.x, (xv.y-mu)*rs*g1v.y + be1v.y),
                 pack2((xv.z-mu)*rs*g1v.z + be1v.z, (xv.w-mu)*rs*g1v.w + be1v.w) };
    *reinterpret_cast<uint2*>(&tile[row*64 + ((l15*4) ^ ((row&7)<<3))]) = pk;
  }

  // ---- phase A: per m-tile attn chain; leaves n2 in the tile ----
  for (int mt=0; mt<4; ++mt){
    const int arow = mt*16 + l15;
    const int asw  = (arow&7)<<3;
    const int abase= arow*64;
    bf16x8 a0 = __builtin_bit_cast(bf16x8, *reinterpret_cast<const u16x8*>(tile + abase + ((     lg*8) ^ asw)));
    bf16x8 a1 = __builtin_bit_cast(bf16x8, *reinterpret_cast<const u16x8*>(tile + abase + ((32 + lg*8) ^ asw)));
    f32x4 qa[4];
    #pragma unroll
    for (int nt=0; nt<4; ++nt){
      f32x4 z = {0.f,0.f,0.f,0.f};
      z = mfma16(a0, WqF[nt*2+0], z);
      z = mfma16(a1, WqF[nt*2+1], z);
      qa[nt] = z;
    }
    #pragma unroll
    for (int nt=0; nt<4; ++nt)
      #pragma unroll
      for (int r=0; r<4; ++r) qa[nt][r] += bqv[nt];
    float mx[4];
    #pragma unroll
    for (int r=0;r<4;++r) mx[r] = fmaxf(fmaxf(qa[0][r],qa[1][r]), fmaxf(qa[2][r],qa[3][r]));
    #pragma unroll
    for (int off=1; off<16; off<<=1)
      #pragma unroll
      for (int r=0;r<4;++r) mx[r] = fmaxf(mx[r], __shfl_xor(mx[r], off, 64));
    float sm[4] = {0.f,0.f,0.f,0.f};
    #pragma unroll
    for (int nt=0;nt<4;++nt)
      #pragma unroll
      for (int r=0;r<4;++r){ float e = __expf(qa[nt][r]-mx[r]); qa[nt][r]=e; sm[r]+=e; }
    #pragma unroll
    for (int off=1; off<16; off<<=1)
      #pragma unroll
      for (int r=0;r<4;++r) sm[r] += __shfl_xor(sm[r], off, 64);
    float inv[4];
    #pragma unroll
    for (int r=0;r<4;++r) inv[r] = 1.f/sm[r];
    #pragma unroll
    for (int nt=0;nt<4;++nt)
      #pragma unroll
      for (int r=0;r<4;++r){
        int row = mt*16 + lg*4 + r, col = nt*16 + l15;
        tile[row*64 + (col ^ ((row&7)<<3))] = f2bf(qa[nt][r]*inv[r]);
      }
    bf16x8 p0 = __builtin_bit_cast(bf16x8, *reinterpret_cast<const u16x8*>(tile + abase + ((     lg*8) ^ asw)));
    bf16x8 p1 = __builtin_bit_cast(bf16x8, *reinterpret_cast<const u16x8*>(tile + abase + ((32 + lg*8) ^ asw)));
    f32x4 ao[4];
    #pragma unroll
    for (int nt=0; nt<4; ++nt){
      f32x4 z = {0.f,0.f,0.f,0.f};
      z = mfma16(p0, CWF[nt*2+0], z);
      z = mfma16(p1, CWF[nt*2+1], z);
      ao[nt] = z;
    }
    float txv[4][4];
    float s1v[4] = {0.f,0.f,0.f,0.f}, s2v[4] = {0.f,0.f,0.f,0.f};
    #pragma unroll
    for (int nt=0;nt<4;++nt)
      #pragma unroll
      for (int r=0;r<4;++r){
        size_t row = (size_t)(tok0 + mt*16 + lg*4 + r);
        float v = ao[nt][r] + brv[nt] + x[row*64 + nt*16+l15];
        g_txb[row*64 + nt*16+l15] = f2bf(v);
        txv[nt][r] = v; s1v[r] += v; s2v[r] += v*v;
      }
    #pragma unroll
    for (int off=1; off<16; off<<=1)
      #pragma unroll
      for (int r=0;r<4;++r){ s1v[r] += __shfl_xor(s1v[r], off, 64); s2v[r] += __shfl_xor(s2v[r], off, 64); }
    #pragma unroll
    for (int r=0;r<4;++r){
      float mu2 = s1v[r]*(1.f/64.f);
      float rs  = rsqrtf(s2v[r]*(1.f/64.f) - mu2*mu2 + 1e-5f);
      s1v[r] = mu2; s2v[r] = rs;
    }
    #pragma unroll
    for (int nt=0;nt<4;++nt)
      #pragma unroll
      for (int r=0;r<4;++r){
        int row = mt*16 + lg*4 + r, col = nt*16 + l15;
        float n2 = (txv[nt][r]-s1v[r])*s2v[r]*g2v[nt] + be2v[nt];
        tile[row*64 + (col ^ ((row&7)<<3))] = f2bf(n2);
      }
  }

  // ---- phase B: h = n2 @ W1^T + b1; mt-outer, register-stash, wide PERMUTED stores ----
  // channel c = nt2*16 + l15 stored at slot c' = l15*16 + nt2  => lane-contiguous rows.
  for (int mt=0; mt<4; ++mt){
    const int arow = mt*16 + l15;
    const int asw  = (arow&7)<<3;
    const int abase= arow*64;
    bf16x8 n20 = __builtin_bit_cast(bf16x8, *reinterpret_cast<const u16x8*>(tile + abase + ((     lg*8) ^ asw)));
    bf16x8 n21 = __builtin_bit_cast(bf16x8, *reinterpret_cast<const u16x8*>(tile + abase + ((32 + lg*8) ^ asw)));
    unsigned hpk[4][8];
    #pragma unroll
    for (int np=0; np<8; ++np){
      bf16x8 wa0 = ldfrag_g(wf + 16384 + (np*4+0)*512 + l*8);
      bf16x8 wa1 = ldfrag_g(wf + 16384 + (np*4+1)*512 + l*8);
      bf16x8 wb0 = ldfrag_g(wf + 16384 + (np*4+2)*512 + l*8);
      bf16x8 wb1 = ldfrag_g(wf + 16384 + (np*4+3)*512 + l*8);
      float ba = b1v[np*2], bb = b1v[np*2+1];
      f32x4 ha = {ba,ba,ba,ba};
      ha = mfma16(n20, wa0, ha);
      ha = mfma16(n21, wa1, ha);
      f32x4 hb = {bb,bb,bb,bb};
      hb = mfma16(n20, wb0, hb);
      hb = mfma16(n21, wb1, hb);
      #pragma unroll
      for (int r=0;r<4;++r) hpk[r][np] = pack2(ha[r], hb[r]);
    }
    #pragma unroll
    for (int r=0;r<4;++r){
      const size_t ro = hbase + (size_t)(mt*16+lg*4+r)*256 + l15*16;
      uint4 v0 = { hpk[r][0], hpk[r][1], hpk[r][2], hpk[r][3] };
      uint4 v1 = { hpk[r][4], hpk[r][5], hpk[r][6], hpk[r][7] };
      *reinterpret_cast<uint4*>(&g_h[ro])   = v0;
      *reinterpret_cast<uint4*>(&g_h[ro+8]) = v1;
    }
  }
}

// ============ k3: depthwise conv3x3 + GELU + W2 — rolling row window ============
// Block = 16 x-tokens x 16 y-rows, 256 thr (4 waves). 4-slot LDS row ring
// (18 tok x 256 ch bf16). Per y-iter: issue next-row loads (T14 split) ->
// conv from LDS (1 ch/lane) -> ds_write staged row -> ONE barrier -> W2 MFMA
// (wave = output quarter) -> fused epilogue. Each g_h row fetched ONCE.
__global__ __launch_bounds__(256,3) void k3_conv_ffn2(
  const unsigned short* __restrict__ g_h,
  const unsigned short* __restrict__ zrow,
  const float* __restrict__ dwp,
  const float* __restrict__ b2,
  const unsigned short* __restrict__ wf,
  const unsigned short* __restrict__ g_txb, float* __restrict__ out)
{
  __shared__ unsigned ring[4][2304];        // 4 slots x 18 tok x 512B = 36 KB
  __shared__ unsigned short obuf[2][4096];  // double-buffered 16tok x 256ch = 16 KB
  const int t = threadIdx.x, w = t>>6, l = t&63;
  const int l15 = l&15, lg = l>>4;
  const int bid = (blockIdx.x & 7)*128 + (blockIdx.x >> 3);   // XCD-chunked remap
  const int img = bid>>6;
  const int r6  = bid&63;
  const int y0  = (r6>>3)*16, x0 = (r6&7)*16;

  // taps + bias for this lane's channel c' = t (k0 pre-permuted, 12-float stride)
  const float4 tA = *reinterpret_cast<const float4*>(&dwp[t*12]);
  const float4 tB = *reinterpret_cast<const float4*>(&dwp[t*12+4]);
  const float4 tC = *reinterpret_cast<const float4*>(&dwp[t*12+8]);  // tap8, bias

  // W2 frags for output quarter ntc = w
  bf16x8 W2F[8];
  #pragma unroll
  for (int q=0;q<8;++q)
    W2F[q] = ldfrag_g(wf + 32768 + (w*8 + q)*512 + l*8);
  const float4 b2q = *reinterpret_cast<const float4*>(&b2[w*16 + lg*4]);

  const int di = w*576 + l;   // per-lane dword index into a row window (+ i*64)

  auto rowsrc = [&](int ri) -> const unsigned* {
    return (ri>=0 && ri<128)
      ? reinterpret_cast<const unsigned*>(g_h + ((size_t)(img*128+ri)*HPITCH + x0)*256)
      : reinterpret_cast<const unsigned*>(zrow + x0*256);
  };

  // prologue: stage rows y0-1, y0, y0+1 into slots 0,1,2
  {
    unsigned st[3][9];
    #pragma unroll
    for (int k=0;k<3;++k){
      const unsigned* src = rowsrc(y0-1+k);
      #pragma unroll
      for (int i=0;i<9;++i) st[k][i] = src[di + i*64];
    }
    #pragma unroll
    for (int k=0;k<3;++k)
      #pragma unroll
      for (int i=0;i<9;++i) ring[k][di + i*64] = st[k][i];
  }
  __syncthreads();

  for (int yy=0; yy<16; ++yy){
    const int gy = y0 + yy;
    // T14 issue-early: loads of row gy+2 into regs
    unsigned rr[9];
    {
      const unsigned* src = rowsrc(gy+2);
      #pragma unroll
      for (int i=0;i<9;++i) rr[i] = src[di + i*64];
    }
    // epilogue residual prefetch
    const size_t gtok = (size_t)img*16384 + (size_t)gy*128 + x0 + l15;
    const u16x4v tq = *reinterpret_cast<const u16x4v*>(&g_txb[gtok*64 + w*16 + lg*4]);

    // conv from LDS ring (rows y-1,y,y+1 = slots yy, yy+1, yy+2 mod 4)
    const unsigned short* rA16 = reinterpret_cast<const unsigned short*>(ring[(yy  )&3]);
    const unsigned short* rB16 = reinterpret_cast<const unsigned short*>(ring[(yy+1)&3]);
    const unsigned short* rC16 = reinterpret_cast<const unsigned short*>(ring[(yy+2)&3]);
    unsigned short* ob = obuf[yy&1];

    float pA=bf2f(rA16[t]),     pB=bf2f(rB16[t]),     pC=bf2f(rC16[t]);
    float cA=bf2f(rA16[256+t]), cB=bf2f(rB16[256+t]), cC=bf2f(rC16[256+t]);
    unsigned short qA=rA16[512+t], qB=rB16[512+t], qC=rC16[512+t];
    #pragma unroll
    for (int s=0;s<16;++s){
      const int o = (s<15 ? (s+3) : 17)*256 + t;   // read-ahead pos s+3
      unsigned short zA=rA16[o], zB=rB16[o], zC=rC16[o];
      float nA=bf2f(qA), nB=bf2f(qB), nC=bf2f(qC);
      float a = tC.y;
      a = fmaf(tA.x,pA, a); a = fmaf(tA.y,cA, a); a = fmaf(tA.z,nA, a);
      a = fmaf(tA.w,pB, a); a = fmaf(tB.x,cB, a); a = fmaf(tB.y,nB, a);
      a = fmaf(tB.z,pC, a); a = fmaf(tB.w,cC, a); a = fmaf(tC.x,nC, a);
      float u2 = a*a;
      float arg = a*(-2.3022082f - 0.1029432f*u2);
      float e = __builtin_amdgcn_exp2f(arg);
      float g = a*__builtin_amdgcn_rcpf(1.f + e);
      ob[s*256 + (t ^ ((s&7)<<3))] = f2bf(g);
      pA=cA; pB=cB; pC=cC; cA=nA; cB=nB; cC=nC; qA=zA; qB=zB; qC=zC;
    }

    // write-late: staged row -> slot (yy+3)&3 (compiler inserts vmcnt wait)
    {
      unsigned* dstr = ring[(yy+3)&3];
      #pragma unroll
      for (int i=0;i<9;++i) dstr[di + i*64] = rr[i];
    }
    __syncthreads();

    // W2 MFMA: wave w computes output quarter w over K=256
    f32x4 oacc = {0.f,0.f,0.f,0.f};
    const int nsw = (l15&7)<<3;
    #pragma unroll
    for (int i=0;i<4;++i){
      bf16x8 fb0 = __builtin_bit_cast(bf16x8,
        *reinterpret_cast<const u16x8*>(&ob[l15*256 + ((i*64      + lg*8) ^ nsw)]));
      bf16x8 fb1 = __builtin_bit_cast(bf16x8,
        *reinterpret_cast<const u16x8*>(&ob[l15*256 + ((i*64 + 32 + lg*8) ^ nsw)]));
      oacc = mfma16(W2F[i*2+0], fb0, oacc);
      oacc = mfma16(W2F[i*2+1], fb1, oacc);
    }
    float4 o;
    o.x = oacc[0] + b2q.x + bf2f(tq[0]);
    o.y = oacc[1] + b2q.y + bf2f(tq[1]);
    o.z = oacc[2] + b2q.z + bf2f(tq[2]);
    o.w = oacc[3] + b2q.w + bf2f(tq[3]);
    *reinterpret_cast<float4*>(&out[gtok*64 + w*16 + lg*4]) = o;
  }
}

extern "C" void kernel_launch(void* const* d_in, const int* in_sizes, int n_in,
                              void* d_out, int out_size, void* d_ws, size_t ws_size,
                              hipStream_t stream)
{
  const float* x  =(const float*)d_in[0];
  const float* g1 =(const float*)d_in[3];
  const float* be1=(const float*)d_in[4];
  const float* Wk =(const float*)d_in[5];
  const float* bk =(const float*)d_in[6];
  const float* Wq =(const float*)d_in[7];
  const float* bq =(const float*)d_in[8];
  const float* Wv =(const float*)d_in[9];
  const float* bv =(const float*)d_in[10];
  const float* Wr =(const float*)d_in[11];
  const float* br =(const float*)d_in[12];
  const float* g2 =(const float*)d_in[13];
  const float* be2=(const float*)d_in[14];
  const float* W1 =(const float*)d_in[15];
  const float* b1 =(const float*)d_in[16];
  const float* dww=(const float*)d_in[17];
  const float* dwb=(const float*)d_in[18];
  const float* W2 =(const float*)d_in[19];
  const float* b2 =(const float*)d_in[20];
  float* outp = (float*)d_out;
  char* ws = (char*)d_ws;

  unsigned short* wfb    = (unsigned short*)ws;                 // 96KB
  unsigned short* ctxWrF = (unsigned short*)(ws + 98304);       // 128KB
  float* g_sump = (float*)(ws + 229376);                        // 128KB
  float* g_part = (float*)(ws + 393216);                        // 8MB
  unsigned short* g_txb = (unsigned short*)(ws + 16777216);     // 32MB bf16
  unsigned short* g_h   = (unsigned short*)(ws + 50331648);     // 136.3MB padded bf16
  unsigned short* zr    = (unsigned short*)(ws + 186646528);    // 65KB zero row
  float* dwp            = (float*)(ws + 186712064);             // 12KB repacked taps+bias

  hipLaunchKernelGGL(k0_wfrag, dim3(97), dim3(64), 0, stream, Wk, Wq, Wv, Wr, W1, W2, dww, dwb, dwp, wfb);
  hipLaunchKernelGGL(zhalo, dim3(2113), dim3(256), 0, stream, (unsigned*)g_h, (unsigned*)zr);
  hipLaunchKernelGGL(k1_ctx, dim3(512), dim3(256), 0, stream, x, g1, be1, bk, bv, wfb, g_part, g_sump);
  hipLaunchKernelGGL(k15_ctxwr, dim3(16), dim3(512), 0, stream, g_part, g_sump, Wr, ctxWrF);
  hipLaunchKernelGGL(k2_attn_ffn1, dim3(1024), dim3(256), 0, stream,
                     x, g1, be1, bq, br, g2, be2, b1, wfb, ctxWrF, g_txb, g_h);
  hipLaunchKernelGGL(k3_conv_ffn2, dim3(1024), dim3(256), 0, stream,
                     g_h, zr, dwp, b2, wfb, g_txb, outp);
}